// Round 2
// baseline (26684.088 us; speedup 1.0000x reference)
//
#include <hip/hip_runtime.h>
#include <hip/hip_bf16.h>

typedef float f32x4 __attribute__((ext_vector_type(4)));
typedef __bf16 bf16x8 __attribute__((ext_vector_type(8)));

#define DEVI static __device__ __forceinline__

DEVI unsigned f2bfu(float f){
  unsigned u = __builtin_bit_cast(unsigned, f);
  return (u + 0x7fffu + ((u >> 16) & 1u)) >> 16;   // RNE f32->bf16
}
DEVI float bf2f(unsigned s){
  return __builtin_bit_cast(float, s << 16);
}
DEVI float sigf(float x){ return 1.f/(1.f + __expf(-x)); }
DEVI float thf(float x){ return 2.f*sigf(2.f*x) - 1.f; }

// ---------------------------------------------------------------------------
// Pack LSTM weights (4 LSTMs) into A-fragment-linear bf16 layout.
// W_aug is (288 x 1024): rows 0..255 = Whh, rows 256+ = Wih, rest 0.
// frag (lstm, w(0..15), kt(0..8), g(0..3)); element (lane, j):
//   value = W_aug[32*kt + 8*(l>>4) + j][256*g + 16*w + (l&15)]
// buffer idx = ((((lstm*16 + w)*9 + kt)*4 + g)*64 + l)*8 + j
// ---------------------------------------------------------------------------
__global__ __launch_bounds__(256) void k_pack_lstm(
    const float* __restrict__ encWhh, const float* __restrict__ encWih,
    const float* __restrict__ decWhh, const float* __restrict__ decWih,
    unsigned short* __restrict__ outp)
{
  const int total = 4*16*9*4*64*8;
  for (int e = blockIdx.x*blockDim.x + threadIdx.x; e < total; e += gridDim.x*blockDim.x){
    int j  = e & 7;
    int l  = (e >> 3) & 63;
    int g  = (e >> 9) & 3;
    int r  = e >> 11;          // (lstm*16 + w)*9 + kt
    int kt = r % 9;  r /= 9;
    int w  = r & 15;
    int lstm = r >> 4;
    int k = 32*kt + 8*(l >> 4) + j;
    int n = 256*g + 16*w + (l & 15);
    float v = 0.f;
    if (lstm < 3){
      if (k < 256)      v = encWhh[(lstm*256 + k)*1024 + n];
      else if (k < 259) v = encWih[(lstm*3 + (k-256))*1024 + n];
    } else {
      if (k < 256)      v = decWhh[k*1024 + n];
      else if (k < 260) v = decWih[(k-256)*1024 + n];
    }
    outp[e] = (unsigned short)f2bfu(v);
  }
}

// ---------------------------------------------------------------------------
// Pack projection weights (K x 256 f32) into B-fragment-linear bf16.
// layout: (((tn*KT + kt)*8 + nt)*64 + lane)*8 + j ; tn in {0,1} (128-col tiles)
// ---------------------------------------------------------------------------
__global__ __launch_bounds__(256) void k_pack_B(
    const float* __restrict__ W, int KT, unsigned short* __restrict__ outp)
{
  const int total = 2*KT*8*64*8;
  for (int e = blockIdx.x*blockDim.x + threadIdx.x; e < total; e += gridDim.x*blockDim.x){
    int j  = e & 7;
    int l  = (e >> 3) & 63;
    int nt = (e >> 9) & 7;
    int r  = e >> 12;          // tn*KT + kt
    int kt = r % KT;
    int tn = r / KT;
    int k = 32*kt + 8*(l >> 4) + j;
    int n = 128*tn + 16*nt + (l & 15);
    outp[e] = (unsigned short)f2bfu(W[k*256 + n]);
  }
}

// ---------------------------------------------------------------------------
// Projection GEMM: C = A(16384xK) * B(Kx256) + bias, then tanh -> bf16 buffer.
// 128x128 tile, BK=32, 4 waves (2x2), mfma_f32_16x16x32_bf16.
// ---------------------------------------------------------------------------
__global__ __launch_bounds__(256) void k_proj(
    const float* __restrict__ A, const unsigned short* __restrict__ Bp,
    const float* __restrict__ bias, unsigned short* __restrict__ outT, int K)
{
  __shared__ unsigned char sA[8192];
  __shared__ unsigned char sB[8192];
  const int tid = threadIdx.x;
  const int l = tid & 63;
  const int wv = tid >> 6;
  const int wm = wv >> 1, wn = wv & 1;
  const int tm = blockIdx.x, tn = blockIdx.y;
  const int KT = K >> 5;

  f32x4 acc[4][4];
  #pragma unroll
  for (int a = 0; a < 4; ++a)
    #pragma unroll
    for (int cc = 0; cc < 4; ++cc)
      acc[a][cc] = f32x4{0.f,0.f,0.f,0.f};

  const int arow = tid >> 1;
  const float* Ap = A + (size_t)(tm*128 + arow)*K + (tid & 1)*16;
  const uint4* Bsrc = (const uint4*)Bp + (size_t)tn*KT*512 + tid*2;

  for (int kt = 0; kt < KT; ++kt){
    float4 f0 = *(const float4*)(Ap + kt*32);
    float4 f1 = *(const float4*)(Ap + kt*32 + 4);
    float4 f2 = *(const float4*)(Ap + kt*32 + 8);
    float4 f3 = *(const float4*)(Ap + kt*32 + 12);
    uint4 p0, p1;
    p0.x = f2bfu(f0.x) | (f2bfu(f0.y) << 16);
    p0.y = f2bfu(f0.z) | (f2bfu(f0.w) << 16);
    p0.z = f2bfu(f1.x) | (f2bfu(f1.y) << 16);
    p0.w = f2bfu(f1.z) | (f2bfu(f1.w) << 16);
    p1.x = f2bfu(f2.x) | (f2bfu(f2.y) << 16);
    p1.y = f2bfu(f2.z) | (f2bfu(f2.w) << 16);
    p1.z = f2bfu(f3.x) | (f2bfu(f3.y) << 16);
    p1.w = f2bfu(f3.z) | (f2bfu(f3.w) << 16);
    unsigned base = arow*64 + (tid & 1)*32;
    unsigned sw = (arow & 3) << 4;
    *(uint4*)(sA + ((base)      ^ sw)) = p0;
    *(uint4*)(sA + ((base + 16) ^ sw)) = p1;
    *((uint4*)sB + tid*2)     = Bsrc[kt*512];
    *((uint4*)sB + tid*2 + 1) = Bsrc[kt*512 + 1];
    __syncthreads();

    bf16x8 af[4], bf[4];
    #pragma unroll
    for (int a = 0; a < 4; ++a){
      unsigned row = 64*wm + 16*a + (l & 15);
      unsigned off = (row*64 + 16*(l >> 4)) ^ ((row & 3) << 4);
      af[a] = __builtin_bit_cast(bf16x8, *(const uint4*)(sA + off));
    }
    #pragma unroll
    for (int cc = 0; cc < 4; ++cc){
      unsigned off = ((4*wn + cc)*64 + l)*16;
      bf[cc] = __builtin_bit_cast(bf16x8, *(const uint4*)(sB + off));
    }
    #pragma unroll
    for (int a = 0; a < 4; ++a)
      #pragma unroll
      for (int cc = 0; cc < 4; ++cc)
        acc[a][cc] = __builtin_amdgcn_mfma_f32_16x16x32_bf16(af[a], bf[cc], acc[a][cc], 0, 0, 0);
    __syncthreads();
  }
  #pragma unroll
  for (int cc = 0; cc < 4; ++cc){
    int colg = tn*128 + 64*wn + 16*cc + (l & 15);
    float bs = bias[colg];
    #pragma unroll
    for (int a = 0; a < 4; ++a){
      int rowg = tm*128 + 64*wm + 16*a + 4*(l >> 4);
      #pragma unroll
      for (int r = 0; r < 4; ++r){
        outT[(size_t)(rowg + r)*256 + colg] = (unsigned short)f2bfu(thf(acc[a][cc][r] + bs));
      }
    }
  }
}

// ---------------------------------------------------------------------------
// Attention scalar dots. 7 partial dots -> 6 score fields (6,B,T) f32.
// ---------------------------------------------------------------------------
__global__ __launch_bounds__(256) void k_attdot(
    const unsigned short* __restrict__ tT, const unsigned short* __restrict__ tF,
    const unsigned short* __restrict__ tA,
    const float* __restrict__ attW, const float* __restrict__ utW,
    const float* __restrict__ ufW, const float* __restrict__ uaW,
    float* __restrict__ s6)
{
  const int l = threadIdx.x & 63;
  const int wid = (blockIdx.x*blockDim.x + threadIdx.x) >> 6;
  const int nw = (gridDim.x*blockDim.x) >> 6;
  float alo[4], ahi[4], wt[4], wf[4], wa[4];
  #pragma unroll
  for (int q = 0; q < 4; ++q){
    alo[q] = attW[4*l + q];
    ahi[q] = attW[256 + 4*l + q];
    wt[q]  = utW[4*l + q];
    wf[q]  = ufW[4*l + q];
    wa[q]  = uaW[4*l + q];
  }
  for (int r = wid; r < 16384; r += nw){
    uint2 vT = *(const uint2*)(tT + (size_t)r*256 + 4*l);
    uint2 vF = *(const uint2*)(tF + (size_t)r*256 + 4*l);
    uint2 vA = *(const uint2*)(tA + (size_t)r*256 + 4*l);
    float xt[4] = { bf2f(vT.x & 0xffff), bf2f(vT.x >> 16), bf2f(vT.y & 0xffff), bf2f(vT.y >> 16) };
    float xf[4] = { bf2f(vF.x & 0xffff), bf2f(vF.x >> 16), bf2f(vF.y & 0xffff), bf2f(vF.y >> 16) };
    float xa[4] = { bf2f(vA.x & 0xffff), bf2f(vA.x >> 16), bf2f(vA.y & 0xffff), bf2f(vA.y >> 16) };
    float ptlo = 0.f, ptu = 0.f, pflo = 0.f, pfhi = 0.f, pfu = 0.f, pahi = 0.f, pau = 0.f;
    #pragma unroll
    for (int q = 0; q < 4; ++q){
      ptlo += xt[q]*alo[q]; ptu += xt[q]*wt[q];
      pflo += xf[q]*alo[q]; pfhi += xf[q]*ahi[q]; pfu += xf[q]*wf[q];
      pahi += xa[q]*ahi[q]; pau += xa[q]*wa[q];
    }
    #pragma unroll
    for (int s = 1; s < 64; s <<= 1){
      ptlo += __shfl_xor(ptlo, s); ptu  += __shfl_xor(ptu, s);
      pflo += __shfl_xor(pflo, s); pfhi += __shfl_xor(pfhi, s);
      pfu  += __shfl_xor(pfu, s);  pahi += __shfl_xor(pahi, s);
      pau  += __shfl_xor(pau, s);
    }
    if (l == 0){
      int o = r;
      s6[o]             = ptlo + pfhi;
      s6[16384 + o]     = pflo + pahi;
      s6[2*16384 + o]   = ptlo + pahi;
      s6[3*16384 + o]   = ptu;
      s6[4*16384 + o]   = pfu;
      s6[5*16384 + o]   = pau;
    }
  }
}

// ---------------------------------------------------------------------------
__global__ __launch_bounds__(256) void k_zerofeed(unsigned short* __restrict__ encfeed)
{
  int i = blockIdx.x*blockDim.x + threadIdx.x;
  if (i < 16384) encfeed[i*4 + 3] = 0;
}

// ---------------------------------------------------------------------------
// Softmax over T per (field,b). Fields 0..2 -> attn_tb f32 (t*16+b)*3+k.
// Fields 3..5 -> encfeed bf16 (t*16+b)*4+k (scrambled reshape honored).
// ---------------------------------------------------------------------------
__global__ __launch_bounds__(256) void k_smax(
    const float* __restrict__ s6, float* __restrict__ attn_tb,
    unsigned short* __restrict__ encfeed)
{
  __shared__ float red[4];
  const int f = blockIdx.x >> 4;
  const int b = blockIdx.x & 15;
  const int tid = threadIdx.x;
  const float* row = s6 + f*16384 + b*1024;
  float4 v = *(const float4*)(row + 4*tid);
  float mx = fmaxf(fmaxf(v.x, v.y), fmaxf(v.z, v.w));
  #pragma unroll
  for (int s = 1; s < 64; s <<= 1) mx = fmaxf(mx, __shfl_xor(mx, s));
  if ((tid & 63) == 0) red[tid >> 6] = mx;
  __syncthreads();
  mx = fmaxf(fmaxf(red[0], red[1]), fmaxf(red[2], red[3]));
  float e0 = __expf(v.x - mx), e1 = __expf(v.y - mx), e2 = __expf(v.z - mx), e3 = __expf(v.w - mx);
  float sm = e0 + e1 + e2 + e3;
  __syncthreads();
  #pragma unroll
  for (int s = 1; s < 64; s <<= 1) sm += __shfl_xor(sm, s);
  if ((tid & 63) == 0) red[tid >> 6] = sm;
  __syncthreads();
  sm = red[0] + red[1] + red[2] + red[3];
  float inv = 1.f/sm;
  float e[4] = {e0, e1, e2, e3};
  int ff = (f < 3) ? f : f - 3;
  #pragma unroll
  for (int q = 0; q < 4; ++q){
    int idx = ff*1024 + 4*tid + q;
    int tt = idx/3, kk = idx - 3*tt;
    if (f < 3) attn_tb[(tt*16 + b)*3 + kk] = e[q]*inv;
    else       encfeed[(tt*16 + b)*4 + kk] = (unsigned short)f2bfu(e[q]*inv);
  }
}

// ---------------------------------------------------------------------------
// Decoder feed: decfeed[t,b,0] = shifted target; [t,b,1+k] = context(t,b,k)
//   context = sum_m attn[t,b,m] * enc_out[t-m,b,k]  (t-m >= 0)
// ---------------------------------------------------------------------------
__global__ __launch_bounds__(256) void k_ctx(
    const float* __restrict__ attn_tb, const float* __restrict__ enc_out_tb,
    const float* __restrict__ target, unsigned short* __restrict__ decfeed)
{
  int i = blockIdx.x*blockDim.x + threadIdx.x;   // t*16 + b
  if (i >= 16384) return;
  int t = i >> 4, b = i & 15;
  float a0 = attn_tb[i*3], a1 = attn_tb[i*3+1], a2 = attn_tb[i*3+2];
  unsigned o[4];
  o[0] = f2bfu(t > 0 ? target[b*1024 + t - 1] : 0.f);
  #pragma unroll
  for (int k = 0; k < 3; ++k){
    float s = a0 * enc_out_tb[i*3 + k];
    if (t >= 1) s += a1 * enc_out_tb[(i-16)*3 + k];
    if (t >= 2) s += a2 * enc_out_tb[(i-32)*3 + k];
    o[k+1] = f2bfu(s);
  }
  uint2 pk; pk.x = o[0] | (o[1] << 16); pk.y = o[2] | (o[3] << 16);
  *(uint2*)(decfeed + (size_t)i*4) = pk;
}

// ---------------------------------------------------------------------------
// LSTM recurrence. 1024 threads = 16 waves; wave w owns h-cols [16w,16w+16).
// Weights register-resident (36 A-frags/wave). W as MFMA A-operand, h as B:
// D col = batch (l&15), D rows = 4 h-cols (4*(l>>4)+r) -> cell epilogue fully
// in registers, c-state in registers, h double-buffered in LDS, 1 barrier/step.
// ---------------------------------------------------------------------------
__global__ __launch_bounds__(1024, 4) void k_lstm(
    const unsigned short* __restrict__ packW,
    const unsigned short* __restrict__ encfeed,
    const unsigned short* __restrict__ decfeed,
    const float* __restrict__ enc_b,
    const float* __restrict__ dec_b,
    const float* __restrict__ dec_h0,
    const float* __restrict__ dec_c0,
    unsigned short* __restrict__ enc_h,
    unsigned short* __restrict__ dec_h,
    int lstm0)
{
  __shared__ unsigned char hl[2][16*768];   // bf16 [b][k 0..287], row 768B, XOR swizzle
  const int tid = threadIdx.x;
  const int l = tid & 63;
  const int w = tid >> 6;                   // 0..15
  const int lstm = lstm0 + blockIdx.x;
  const bool isdec = (lstm == 3);
  const unsigned short* feed = isdec ? decfeed : encfeed;
  const float* bsrc = isdec ? dec_b : (enc_b + lstm*1024);
  unsigned short* hout = isdec ? dec_h : (enc_h + (size_t)lstm*1024*16*256);

  const int b = l & 15;
  const int j0 = 16*w + 4*(l >> 4);
  const unsigned swb = (unsigned)(b & 7) << 4;

  float bias[4][4];
  #pragma unroll
  for (int g = 0; g < 4; ++g)
    #pragma unroll
    for (int r = 0; r < 4; ++r)
      bias[g][r] = bsrc[g*256 + j0 + r];

  float c[4];
  #pragma unroll
  for (int r = 0; r < 4; ++r) c[r] = isdec ? dec_c0[j0 + r] : 0.f;

  // init h0 into buf0
  uint2 hz;
  if (isdec){
    hz.x = f2bfu(dec_h0[j0])     | (f2bfu(dec_h0[j0+1]) << 16);
    hz.y = f2bfu(dec_h0[j0+2])   | (f2bfu(dec_h0[j0+3]) << 16);
  } else { hz.x = 0u; hz.y = 0u; }
  *(uint2*)(hl[0] + ((b*768 + 2*j0) ^ swb)) = hz;

  // zero pad cols 260..287 (bytes 520..575) in both buffers
  if (tid < 224){
    int bufi = tid / 112;
    int r = tid % 112;
    int bb = r / 7, q = r % 7;
    uint2 z; z.x = 0u; z.y = 0u;
    *(uint2*)(hl[bufi] + ((bb*768 + 520 + 8*q) ^ ((unsigned)(bb & 7) << 4))) = z;
  }
  // x(0) into buf0
  if (tid < 16){
    uint2 gx0 = *(const uint2*)(feed + tid*4);
    *(uint2*)(hl[0] + ((tid*768 + 512) ^ ((unsigned)(tid & 7) << 4))) = gx0;
  }

  // preload 36 weight fragments into registers
  const uint4* wb = (const uint4*)packW + ((size_t)(lstm*16 + w)*36)*64 + l;
  uint4 wreg[36];
  #pragma unroll
  for (int i = 0; i < 36; ++i) wreg[i] = wb[i*64];

  __syncthreads();

  for (int t = 0; t < 1024; ++t){
    const unsigned char* cur = hl[t & 1];
    unsigned char* nxt = (unsigned char*)hl[(t + 1) & 1];

    // B-frags: h_aug for this batch-column group
    bf16x8 af[9];
    #pragma unroll
    for (int kt = 0; kt < 9; ++kt){
      unsigned off = (unsigned)(b*768 + kt*64 + 16*(l >> 4)) ^ swb;
      af[kt] = __builtin_bit_cast(bf16x8, *(const uint4*)(cur + off));
    }

    // prefetch x(t+1)
    uint2 gx;
    const bool ldx = (t < 1023) && (tid < 16);
    if (ldx) gx = *(const uint2*)(feed + (size_t)(t + 1)*64 + tid*4);

    f32x4 acc[4];
    #pragma unroll
    for (int g = 0; g < 4; ++g) acc[g] = f32x4{0.f,0.f,0.f,0.f};
    #pragma unroll
    for (int kt = 0; kt < 9; ++kt){
      #pragma unroll
      for (int g = 0; g < 4; ++g)
        acc[g] = __builtin_amdgcn_mfma_f32_16x16x32_bf16(
            __builtin_bit_cast(bf16x8, wreg[kt*4 + g]), af[kt], acc[g], 0, 0, 0);
    }

    // cell epilogue fully in registers
    unsigned hp[4];
    #pragma unroll
    for (int r = 0; r < 4; ++r){
      float vi = sigf(acc[0][r] + bias[0][r]);
      float vf = sigf(acc[1][r] + bias[1][r]);
      float vg = thf (acc[2][r] + bias[2][r]);
      float vo = sigf(acc[3][r] + bias[3][r]);
      float cc = vf*c[r] + vi*vg;
      c[r] = cc;
      hp[r] = f2bfu(vo * thf(cc));
    }
    uint2 hpk; hpk.x = hp[0] | (hp[1] << 16); hpk.y = hp[2] | (hp[3] << 16);
    *(uint2*)(nxt + ((b*768 + 2*j0) ^ swb)) = hpk;
    *(uint2*)(hout + (size_t)(t*16 + b)*256 + j0) = hpk;
    if (ldx) *(uint2*)(nxt + ((tid*768 + 512) ^ ((unsigned)(tid & 7) << 4))) = gx;
    __syncthreads();
  }
}

// ---------------------------------------------------------------------------
// enc_out[t,b,k] = enc_h[k,t,b,:] . enc_outW[k,:] + enc_outb[k]
// ---------------------------------------------------------------------------
__global__ __launch_bounds__(256) void k_encout(
    const unsigned short* __restrict__ enc_h, const float* __restrict__ outW,
    const float* __restrict__ outb, float* __restrict__ enc_out_tb)
{
  const int l = threadIdx.x & 63;
  const int wid = (blockIdx.x*blockDim.x + threadIdx.x) >> 6;
  const int nw = (gridDim.x*blockDim.x) >> 6;
  for (int e = wid; e < 3*1024*16; e += nw){
    int k = e >> 14;
    int t = (e >> 4) & 1023;
    int b = e & 15;
    uint2 v = *(const uint2*)(enc_h + ((size_t)(k*1024 + t)*16 + b)*256 + 4*l);
    float p = bf2f(v.x & 0xffff)*outW[k*256 + 4*l]
            + bf2f(v.x >> 16)   *outW[k*256 + 4*l + 1]
            + bf2f(v.y & 0xffff)*outW[k*256 + 4*l + 2]
            + bf2f(v.y >> 16)   *outW[k*256 + 4*l + 3];
    #pragma unroll
    for (int s = 1; s < 64; s <<= 1) p += __shfl_xor(p, s);
    if (l == 0) enc_out_tb[(t*16 + b)*3 + k] = p + outb[k];
  }
}

// ---------------------------------------------------------------------------
// y[b,t] = relu(dec_h[t,b,:] @ W1 + b1) @ W2 + b2
// ---------------------------------------------------------------------------
__global__ __launch_bounds__(256) void k_decout(
    const unsigned short* __restrict__ dec_h, const float* __restrict__ W1,
    const float* __restrict__ b1, const float* __restrict__ W2,
    const float* __restrict__ b2, float* __restrict__ out)
{
  const int l = threadIdx.x & 63;
  const int wid = (blockIdx.x*blockDim.x + threadIdx.x) >> 6;
  const int nw = (gridDim.x*blockDim.x) >> 6;
  const int o = l >> 4, jc = l & 15;
  for (int e = wid; e < 16384; e += nw){
    int t = e >> 4, b = e & 15;
    const unsigned short* hr = dec_h + (size_t)(t*16 + b)*256 + jc*16;
    uint4 v0 = *(const uint4*)hr;
    uint4 v1 = *(const uint4*)(hr + 8);
    unsigned vv[8] = {v0.x, v0.y, v0.z, v0.w, v1.x, v1.y, v1.z, v1.w};
    float p = 0.f;
    #pragma unroll
    for (int q = 0; q < 8; ++q){
      int j = jc*16 + 2*q;
      p += bf2f(vv[q] & 0xffff) * W1[j*4 + o];
      p += bf2f(vv[q] >> 16)    * W1[(j + 1)*4 + o];
    }
    p += __shfl_xor(p, 1); p += __shfl_xor(p, 2);
    p += __shfl_xor(p, 4); p += __shfl_xor(p, 8);
    float v = 0.f;
    if (jc == 0) v = fmaxf(p + b1[o], 0.f) * W2[o];
    v += __shfl_xor(v, 16);
    v += __shfl_xor(v, 32);
    if (l == 0) out[b*1024 + t] = v + b2[0];
  }
}

// ---------------------------------------------------------------------------
extern "C" void kernel_launch(void* const* d_in, const int* in_sizes, int n_in,
                              void* d_out, int out_size, void* d_ws, size_t ws_size,
                              hipStream_t stream)
{
  const float* faceF   = (const float*)d_in[1];
  const float* audioF  = (const float*)d_in[2];
  const float* textF   = (const float*)d_in[3];
  const float* target  = (const float*)d_in[4];
  const float* textW   = (const float*)d_in[5];
  const float* textB   = (const float*)d_in[6];
  const float* faceW   = (const float*)d_in[7];
  const float* faceB   = (const float*)d_in[8];
  const float* audioW  = (const float*)d_in[9];
  const float* audioB  = (const float*)d_in[10];
  const float* attW    = (const float*)d_in[11];
  const float* utW     = (const float*)d_in[13];
  const float* ufW     = (const float*)d_in[15];
  const float* uaW     = (const float*)d_in[17];
  const float* encWih  = (const float*)d_in[19];
  const float* encWhh  = (const float*)d_in[20];
  const float* encB    = (const float*)d_in[21];
  const float* encOutW = (const float*)d_in[22];
  const float* encOutB = (const float*)d_in[23];
  const float* decWih  = (const float*)d_in[24];
  const float* decWhh  = (const float*)d_in[25];
  const float* decB    = (const float*)d_in[26];
  const float* decH0   = (const float*)d_in[27];
  const float* decC0   = (const float*)d_in[28];
  const float* out1W   = (const float*)d_in[29];
  const float* out1B   = (const float*)d_in[30];
  const float* out2W   = (const float*)d_in[31];
  const float* out2B   = (const float*)d_in[32];
  float* out = (float*)d_out;

  char* ws = (char*)d_ws;
  size_t off = 0;
  auto alloc = [&](size_t bytes) -> void* {
    void* p = ws + off;
    off += (bytes + 255) & ~(size_t)255;
    return p;
  };
  unsigned short* packL   = (unsigned short*)alloc(1179648ull*2);
  unsigned short* packT   = (unsigned short*)alloc(196608ull*2);
  unsigned short* packF   = (unsigned short*)alloc(131072ull*2);
  unsigned short* packA   = (unsigned short*)alloc(65536ull*2);
  unsigned short* tanhT   = (unsigned short*)alloc(16384ull*256*2);
  unsigned short* tanhF   = (unsigned short*)alloc(16384ull*256*2);
  unsigned short* tanhA   = (unsigned short*)alloc(16384ull*256*2);
  float*          s6      = (float*)alloc(6ull*16384*4);
  float*          attn_tb = (float*)alloc(49152ull*4);
  unsigned short* encfeed = (unsigned short*)alloc(65536ull*2);
  unsigned short* decfeed = (unsigned short*)alloc(65536ull*2);
  unsigned short* enc_h   = (unsigned short*)alloc(3ull*1024*16*256*2);
  float*          enc_out_tb = (float*)alloc(49152ull*4);
  unsigned short* dec_h   = (unsigned short*)alloc(1024ull*16*256*2);
  if (off > ws_size) return;

  hipLaunchKernelGGL(k_pack_lstm, dim3(512), dim3(256), 0, stream,
                     encWhh, encWih, decWhh, decWih, packL);
  hipLaunchKernelGGL(k_pack_B, dim3(256), dim3(256), 0, stream, textW, 24, packT);
  hipLaunchKernelGGL(k_pack_B, dim3(256), dim3(256), 0, stream, faceW, 16, packF);
  hipLaunchKernelGGL(k_pack_B, dim3(128), dim3(256), 0, stream, audioW, 8, packA);

  hipLaunchKernelGGL(k_proj, dim3(128, 2), dim3(256), 0, stream, textF,  packT, textB,  tanhT, 768);
  hipLaunchKernelGGL(k_proj, dim3(128, 2), dim3(256), 0, stream, faceF,  packF, faceB,  tanhF, 512);
  hipLaunchKernelGGL(k_proj, dim3(128, 2), dim3(256), 0, stream, audioF, packA, audioB, tanhA, 256);

  hipLaunchKernelGGL(k_attdot, dim3(256), dim3(256), 0, stream,
                     tanhT, tanhF, tanhA, attW, utW, ufW, uaW, s6);
  hipLaunchKernelGGL(k_zerofeed, dim3(64), dim3(256), 0, stream, encfeed);
  hipLaunchKernelGGL(k_smax, dim3(96), dim3(256), 0, stream, s6, attn_tb, encfeed);

  // dynamic LDS pad: 24576 static + 57344 = 81920 B > 80K -> one block per CU
  hipLaunchKernelGGL(k_lstm, dim3(3), dim3(1024), 57344, stream,
                     packL, encfeed, decfeed, encB, decB, decH0, decC0,
                     enc_h, dec_h, 0);
  hipLaunchKernelGGL(k_encout, dim3(256), dim3(256), 0, stream,
                     enc_h, encOutW, encOutB, enc_out_tb);
  hipLaunchKernelGGL(k_ctx, dim3(64), dim3(256), 0, stream,
                     attn_tb, enc_out_tb, target, decfeed);
  hipLaunchKernelGGL(k_lstm, dim3(1), dim3(1024), 57344, stream,
                     packL, encfeed, decfeed, encB, decB, decH0, decC0,
                     enc_h, dec_h, 3);
  hipLaunchKernelGGL(k_decout, dim3(256), dim3(256), 0, stream,
                     dec_h, out1W, out1B, out2W, out2B, out);
}

// Round 3
// 19971.519 us; speedup vs baseline: 1.3361x; 1.3361x over previous
//
#include <hip/hip_runtime.h>
#include <hip/hip_bf16.h>

typedef float f32x4 __attribute__((ext_vector_type(4)));
typedef __bf16 bf16x8 __attribute__((ext_vector_type(8)));
typedef unsigned long long ull;

#define DEVI static __device__ __forceinline__

DEVI unsigned f2bfu(float f){
  unsigned u = __builtin_bit_cast(unsigned, f);
  return (u + 0x7fffu + ((u >> 16) & 1u)) >> 16;   // RNE f32->bf16
}
DEVI float bf2f(unsigned s){
  return __builtin_bit_cast(float, s << 16);
}
DEVI float sigf(float x){ return 1.f/(1.f + __expf(-x)); }
DEVI float thf(float x){ return 2.f*sigf(2.f*x) - 1.f; }

// ---------------------------------------------------------------------------
// Pack LSTM weights (4 LSTMs) into A-fragment-linear bf16 layout.
// W_aug is (288 x 1024): rows 0..255 = Whh, rows 256+ = Wih, row 260 = bias
// (consumed by a constant-1.0 input row), rest 0.
// frag (lstm, wglob(0..15), kt(0..8), g(0..3)); element (lane, j):
//   value = W_aug[32*kt + 8*(l>>4) + j][256*g + 16*wglob + (l&15)]
// ---------------------------------------------------------------------------
__global__ __launch_bounds__(256) void k_pack_lstm(
    const float* __restrict__ encWhh, const float* __restrict__ encWih,
    const float* __restrict__ decWhh, const float* __restrict__ decWih,
    const float* __restrict__ encB,   const float* __restrict__ decB,
    unsigned short* __restrict__ outp)
{
  const int total = 4*16*9*4*64*8;
  for (int e = blockIdx.x*blockDim.x + threadIdx.x; e < total; e += gridDim.x*blockDim.x){
    int j  = e & 7;
    int l  = (e >> 3) & 63;
    int g  = (e >> 9) & 3;
    int r  = e >> 11;          // (lstm*16 + w)*9 + kt
    int kt = r % 9;  r /= 9;
    int w  = r & 15;
    int lstm = r >> 4;
    int k = 32*kt + 8*(l >> 4) + j;
    int n = 256*g + 16*w + (l & 15);
    float v = 0.f;
    if (lstm < 3){
      if (k < 256)       v = encWhh[(lstm*256 + k)*1024 + n];
      else if (k < 259)  v = encWih[(lstm*3 + (k-256))*1024 + n];
      else if (k == 260) v = encB[lstm*1024 + n];
    } else {
      if (k < 256)       v = decWhh[k*1024 + n];
      else if (k < 260)  v = decWih[(k-256)*1024 + n];
      else if (k == 260) v = decB[n];
    }
    outp[e] = (unsigned short)f2bfu(v);
  }
}

// ---------------------------------------------------------------------------
// Pack projection weights (K x 256 f32) into B-fragment-linear bf16.
// ---------------------------------------------------------------------------
__global__ __launch_bounds__(256) void k_pack_B(
    const float* __restrict__ W, int KT, unsigned short* __restrict__ outp)
{
  const int total = 2*KT*8*64*8;
  for (int e = blockIdx.x*blockDim.x + threadIdx.x; e < total; e += gridDim.x*blockDim.x){
    int j  = e & 7;
    int l  = (e >> 3) & 63;
    int nt = (e >> 9) & 7;
    int r  = e >> 12;          // tn*KT + kt
    int kt = r % KT;
    int tn = r / KT;
    int k = 32*kt + 8*(l >> 4) + j;
    int n = 128*tn + 16*nt + (l & 15);
    outp[e] = (unsigned short)f2bfu(W[k*256 + n]);
  }
}

// ---------------------------------------------------------------------------
// Projection GEMM: C = A(16384xK) * B(Kx256) + bias, then tanh -> bf16 buffer.
// ---------------------------------------------------------------------------
__global__ __launch_bounds__(256) void k_proj(
    const float* __restrict__ A, const unsigned short* __restrict__ Bp,
    const float* __restrict__ bias, unsigned short* __restrict__ outT, int K)
{
  __shared__ unsigned char sA[8192];
  __shared__ unsigned char sB[8192];
  const int tid = threadIdx.x;
  const int l = tid & 63;
  const int wv = tid >> 6;
  const int wm = wv >> 1, wn = wv & 1;
  const int tm = blockIdx.x, tn = blockIdx.y;
  const int KT = K >> 5;

  f32x4 acc[4][4];
  #pragma unroll
  for (int a = 0; a < 4; ++a)
    #pragma unroll
    for (int cc = 0; cc < 4; ++cc)
      acc[a][cc] = f32x4{0.f,0.f,0.f,0.f};

  const int arow = tid >> 1;
  const float* Ap = A + (size_t)(tm*128 + arow)*K + (tid & 1)*16;
  const uint4* Bsrc = (const uint4*)Bp + (size_t)tn*KT*512 + tid*2;

  for (int kt = 0; kt < KT; ++kt){
    float4 f0 = *(const float4*)(Ap + kt*32);
    float4 f1 = *(const float4*)(Ap + kt*32 + 4);
    float4 f2 = *(const float4*)(Ap + kt*32 + 8);
    float4 f3 = *(const float4*)(Ap + kt*32 + 12);
    uint4 p0, p1;
    p0.x = f2bfu(f0.x) | (f2bfu(f0.y) << 16);
    p0.y = f2bfu(f0.z) | (f2bfu(f0.w) << 16);
    p0.z = f2bfu(f1.x) | (f2bfu(f1.y) << 16);
    p0.w = f2bfu(f1.z) | (f2bfu(f1.w) << 16);
    p1.x = f2bfu(f2.x) | (f2bfu(f2.y) << 16);
    p1.y = f2bfu(f2.z) | (f2bfu(f2.w) << 16);
    p1.z = f2bfu(f3.x) | (f2bfu(f3.y) << 16);
    p1.w = f2bfu(f3.z) | (f2bfu(f3.w) << 16);
    unsigned base = arow*64 + (tid & 1)*32;
    unsigned sw = (arow & 3) << 4;
    *(uint4*)(sA + ((base)      ^ sw)) = p0;
    *(uint4*)(sA + ((base + 16) ^ sw)) = p1;
    *((uint4*)sB + tid*2)     = Bsrc[kt*512];
    *((uint4*)sB + tid*2 + 1) = Bsrc[kt*512 + 1];
    __syncthreads();

    bf16x8 af[4], bf[4];
    #pragma unroll
    for (int a = 0; a < 4; ++a){
      unsigned row = 64*wm + 16*a + (l & 15);
      unsigned off = (row*64 + 16*(l >> 4)) ^ ((row & 3) << 4);
      af[a] = __builtin_bit_cast(bf16x8, *(const uint4*)(sA + off));
    }
    #pragma unroll
    for (int cc = 0; cc < 4; ++cc){
      unsigned off = ((4*wn + cc)*64 + l)*16;
      bf[cc] = __builtin_bit_cast(bf16x8, *(const uint4*)(sB + off));
    }
    #pragma unroll
    for (int a = 0; a < 4; ++a)
      #pragma unroll
      for (int cc = 0; cc < 4; ++cc)
        acc[a][cc] = __builtin_amdgcn_mfma_f32_16x16x32_bf16(af[a], bf[cc], acc[a][cc], 0, 0, 0);
    __syncthreads();
  }
  #pragma unroll
  for (int cc = 0; cc < 4; ++cc){
    int colg = tn*128 + 64*wn + 16*cc + (l & 15);
    float bs = bias[colg];
    #pragma unroll
    for (int a = 0; a < 4; ++a){
      int rowg = tm*128 + 64*wm + 16*a + 4*(l >> 4);
      #pragma unroll
      for (int r = 0; r < 4; ++r){
        outT[(size_t)(rowg + r)*256 + colg] = (unsigned short)f2bfu(thf(acc[a][cc][r] + bs));
      }
    }
  }
}

// ---------------------------------------------------------------------------
// Attention scalar dots. 7 partial dots -> 6 score fields (6,B,T) f32.
// ---------------------------------------------------------------------------
__global__ __launch_bounds__(256) void k_attdot(
    const unsigned short* __restrict__ tT, const unsigned short* __restrict__ tF,
    const unsigned short* __restrict__ tA,
    const float* __restrict__ attW, const float* __restrict__ utW,
    const float* __restrict__ ufW, const float* __restrict__ uaW,
    float* __restrict__ s6)
{
  const int l = threadIdx.x & 63;
  const int wid = (blockIdx.x*blockDim.x + threadIdx.x) >> 6;
  const int nw = (gridDim.x*blockDim.x) >> 6;
  float alo[4], ahi[4], wt[4], wf[4], wa[4];
  #pragma unroll
  for (int q = 0; q < 4; ++q){
    alo[q] = attW[4*l + q];
    ahi[q] = attW[256 + 4*l + q];
    wt[q]  = utW[4*l + q];
    wf[q]  = ufW[4*l + q];
    wa[q]  = uaW[4*l + q];
  }
  for (int r = wid; r < 16384; r += nw){
    uint2 vT = *(const uint2*)(tT + (size_t)r*256 + 4*l);
    uint2 vF = *(const uint2*)(tF + (size_t)r*256 + 4*l);
    uint2 vA = *(const uint2*)(tA + (size_t)r*256 + 4*l);
    float xt[4] = { bf2f(vT.x & 0xffff), bf2f(vT.x >> 16), bf2f(vT.y & 0xffff), bf2f(vT.y >> 16) };
    float xf[4] = { bf2f(vF.x & 0xffff), bf2f(vF.x >> 16), bf2f(vF.y & 0xffff), bf2f(vF.y >> 16) };
    float xa[4] = { bf2f(vA.x & 0xffff), bf2f(vA.x >> 16), bf2f(vA.y & 0xffff), bf2f(vA.y >> 16) };
    float ptlo = 0.f, ptu = 0.f, pflo = 0.f, pfhi = 0.f, pfu = 0.f, pahi = 0.f, pau = 0.f;
    #pragma unroll
    for (int q = 0; q < 4; ++q){
      ptlo += xt[q]*alo[q]; ptu += xt[q]*wt[q];
      pflo += xf[q]*alo[q]; pfhi += xf[q]*ahi[q]; pfu += xf[q]*wf[q];
      pahi += xa[q]*ahi[q]; pau += xa[q]*wa[q];
    }
    #pragma unroll
    for (int s = 1; s < 64; s <<= 1){
      ptlo += __shfl_xor(ptlo, s); ptu  += __shfl_xor(ptu, s);
      pflo += __shfl_xor(pflo, s); pfhi += __shfl_xor(pfhi, s);
      pfu  += __shfl_xor(pfu, s);  pahi += __shfl_xor(pahi, s);
      pau  += __shfl_xor(pau, s);
    }
    if (l == 0){
      int o = r;
      s6[o]             = ptlo + pfhi;
      s6[16384 + o]     = pflo + pahi;
      s6[2*16384 + o]   = ptlo + pahi;
      s6[3*16384 + o]   = ptu;
      s6[4*16384 + o]   = pfu;
      s6[5*16384 + o]   = pau;
    }
  }
}

// ---------------------------------------------------------------------------
__global__ __launch_bounds__(256) void k_zerofeed(unsigned short* __restrict__ encfeed,
                                                  int* __restrict__ ctr)
{
  int i = blockIdx.x*blockDim.x + threadIdx.x;
  if (i < 16384) encfeed[i*4 + 3] = 0;
  if (i < 8) ctr[i] = 0;
}

// ---------------------------------------------------------------------------
// Softmax over T per (field,b). Fields 0..2 -> attn_tb f32; 3..5 -> encfeed bf16.
// ---------------------------------------------------------------------------
__global__ __launch_bounds__(256) void k_smax(
    const float* __restrict__ s6, float* __restrict__ attn_tb,
    unsigned short* __restrict__ encfeed)
{
  __shared__ float red[4];
  const int f = blockIdx.x >> 4;
  const int b = blockIdx.x & 15;
  const int tid = threadIdx.x;
  const float* row = s6 + f*16384 + b*1024;
  float4 v = *(const float4*)(row + 4*tid);
  float mx = fmaxf(fmaxf(v.x, v.y), fmaxf(v.z, v.w));
  #pragma unroll
  for (int s = 1; s < 64; s <<= 1) mx = fmaxf(mx, __shfl_xor(mx, s));
  if ((tid & 63) == 0) red[tid >> 6] = mx;
  __syncthreads();
  mx = fmaxf(fmaxf(red[0], red[1]), fmaxf(red[2], red[3]));
  float e0 = __expf(v.x - mx), e1 = __expf(v.y - mx), e2 = __expf(v.z - mx), e3 = __expf(v.w - mx);
  float sm = e0 + e1 + e2 + e3;
  __syncthreads();
  #pragma unroll
  for (int s = 1; s < 64; s <<= 1) sm += __shfl_xor(sm, s);
  if ((tid & 63) == 0) red[tid >> 6] = sm;
  __syncthreads();
  sm = red[0] + red[1] + red[2] + red[3];
  float inv = 1.f/sm;
  float e[4] = {e0, e1, e2, e3};
  int ff = (f < 3) ? f : f - 3;
  #pragma unroll
  for (int q = 0; q < 4; ++q){
    int idx = ff*1024 + 4*tid + q;
    int tt = idx/3, kk = idx - 3*tt;
    if (f < 3) attn_tb[(tt*16 + b)*3 + kk] = e[q]*inv;
    else       encfeed[(tt*16 + b)*4 + kk] = (unsigned short)f2bfu(e[q]*inv);
  }
}

// ---------------------------------------------------------------------------
// Decoder feed: decfeed[t,b,0] = shifted target; [t,b,1+k] = context(t,b,k)
// ---------------------------------------------------------------------------
__global__ __launch_bounds__(256) void k_ctx(
    const float* __restrict__ attn_tb, const float* __restrict__ enc_out_tb,
    const float* __restrict__ target, unsigned short* __restrict__ decfeed)
{
  int i = blockIdx.x*blockDim.x + threadIdx.x;   // t*16 + b
  if (i >= 16384) return;
  int t = i >> 4, b = i & 15;
  float a0 = attn_tb[i*3], a1 = attn_tb[i*3+1], a2 = attn_tb[i*3+2];
  unsigned o[4];
  o[0] = f2bfu(t > 0 ? target[b*1024 + t - 1] : 0.f);
  #pragma unroll
  for (int k = 0; k < 3; ++k){
    float s = a0 * enc_out_tb[i*3 + k];
    if (t >= 1) s += a1 * enc_out_tb[(i-16)*3 + k];
    if (t >= 2) s += a2 * enc_out_tb[(i-32)*3 + k];
    o[k+1] = f2bfu(s);
  }
  uint2 pk; pk.x = o[0] | (o[1] << 16); pk.y = o[2] | (o[3] << 16);
  *(uint2*)(decfeed + (size_t)i*4) = pk;
}

// ---------------------------------------------------------------------------
// LSTM recurrence, 2 blocks (CUs) per LSTM, 512 threads = 8 waves each.
// Block `half` owns h-cols [128*half, 128*half+128); wave w owns 16 cols.
// Weights register-resident (36 frags = 144 VGPR/wave, cap 256 via
// __launch_bounds__(512,2)). Halves exchange h through LLC with agent-scope
// atomics: per-wave release atomicAdd on a monotone counter, acquire polls.
// Bias enters via constant-1.0 input row (k=260). One __syncthreads per step.
// ---------------------------------------------------------------------------
__global__ __launch_bounds__(512, 2) void k_lstm(
    const unsigned short* __restrict__ packW,
    const unsigned short* __restrict__ encfeed,
    const unsigned short* __restrict__ decfeed,
    const float* __restrict__ dec_h0,
    const float* __restrict__ dec_c0,
    unsigned short* __restrict__ enc_h,
    unsigned short* __restrict__ dec_h,
    ull* __restrict__ exch,
    int* __restrict__ ctr,
    int lstm0)
{
  __shared__ unsigned char hl[2][16*768];   // bf16 [b][k 0..287], row 768B, XOR swizzle
  const int tid = threadIdx.x;
  const int l = tid & 63;
  const int w = tid >> 6;                   // 0..7
  const int lstm = lstm0 + (blockIdx.x >> 1);
  const int half = blockIdx.x & 1;
  const int wglob = half*8 + w;             // 0..15
  const bool isdec = (lstm == 3);
  const unsigned short* feed = isdec ? decfeed : encfeed;
  unsigned short* hout = isdec ? dec_h : (enc_h + (size_t)lstm*1024*16*256);

  const int b = l & 15;
  const int j0 = 16*wglob + 4*(l >> 4);
  const unsigned swb = (unsigned)(b & 7) << 4;

  float c[4];
  #pragma unroll
  for (int r = 0; r < 4; ++r) c[r] = isdec ? dec_c0[j0 + r] : 0.f;

  // full h(0) into buf0 (both halves): 512 threads x 2 uint2 = 256 cols x 16 b
  {
    int ib = tid >> 5;
    int ic = (tid & 31) * 8;
    #pragma unroll
    for (int q = 0; q < 2; ++q){
      int c0 = ic + 4*q;
      uint2 hz;
      if (isdec){
        hz.x = f2bfu(dec_h0[c0])   | (f2bfu(dec_h0[c0+1]) << 16);
        hz.y = f2bfu(dec_h0[c0+2]) | (f2bfu(dec_h0[c0+3]) << 16);
      } else { hz.x = 0u; hz.y = 0u; }
      *(uint2*)(hl[0] + ((ib*768 + 2*c0) ^ ((unsigned)(ib & 7) << 4))) = hz;
    }
  }
  // rows 260..287 in both buffers: row 260 = 1.0 (bias row), rest 0
  if (tid < 224){
    int bufi = tid / 112;
    int r = tid % 112;
    int bb = r / 7, q = r % 7;
    uint2 z;
    z.x = (q == 0) ? 0x00003f80u : 0u;  // col260=1.0 bf16, col261=0
    z.y = 0u;
    *(uint2*)(hl[bufi] + ((bb*768 + 520 + 8*q) ^ ((unsigned)(bb & 7) << 4))) = z;
  }
  // x(0) rows 256..259 into buf0
  if (tid < 16){
    uint2 gx0 = *(const uint2*)(feed + tid*4);
    *(uint2*)(hl[0] + ((tid*768 + 512) ^ ((unsigned)(tid & 7) << 4))) = gx0;
  }

  // preload 36 weight fragments into registers (144 VGPRs)
  const uint4* wb = (const uint4*)packW + ((size_t)(lstm*16 + wglob)*36)*64 + l;
  uint4 wreg[36];
  #pragma unroll
  for (int i = 0; i < 36; ++i) wreg[i] = wb[i*64];

  int* myctr = ctr + lstm*2 + half;
  int* pctr  = ctr + lstm*2 + (half^1);

  __syncthreads();

  for (int t = 0; t < 1024; ++t){
    const unsigned char* cur = hl[t & 1];
    unsigned char* nxt = (unsigned char*)hl[(t + 1) & 1];

    // B-frags: h_aug for this batch column
    bf16x8 af[9];
    #pragma unroll
    for (int kt = 0; kt < 9; ++kt){
      unsigned off = (unsigned)(b*768 + kt*64 + 16*(l >> 4)) ^ swb;
      af[kt] = __builtin_bit_cast(bf16x8, *(const uint4*)(cur + off));
    }

    // prefetch x(t+1)
    uint2 gx;
    const bool ldx = (t < 1023) && (tid < 16);
    if (ldx) gx = *(const uint2*)(feed + (size_t)(t + 1)*64 + tid*4);

    f32x4 acc[4];
    #pragma unroll
    for (int g = 0; g < 4; ++g) acc[g] = f32x4{0.f,0.f,0.f,0.f};
    #pragma unroll
    for (int kt = 0; kt < 9; ++kt){
      #pragma unroll
      for (int g = 0; g < 4; ++g)
        acc[g] = __builtin_amdgcn_mfma_f32_16x16x32_bf16(
            __builtin_bit_cast(bf16x8, wreg[kt*4 + g]), af[kt], acc[g], 0, 0, 0);
    }

    // cell epilogue fully in registers (bias already in acc via k=260 row)
    unsigned hp[4];
    #pragma unroll
    for (int r = 0; r < 4; ++r){
      float vi = sigf(acc[0][r]);
      float vf = sigf(acc[1][r]);
      float vg = thf (acc[2][r]);
      float vo = sigf(acc[3][r]);
      float cc = vf*c[r] + vi*vg;
      c[r] = cc;
      hp[r] = f2bfu(vo * thf(cc));
    }
    uint2 hpk; hpk.x = hp[0] | (hp[1] << 16); hpk.y = hp[2] | (hp[3] << 16);
    *(uint2*)(nxt + ((b*768 + 2*j0) ^ swb)) = hpk;
    *(uint2*)(hout + (size_t)(t*16 + b)*256 + j0) = hpk;

    if (t < 1023){
      const int bufi = (t + 1) & 1;
      // publish own half to LLC
      ull val = ((ull)hpk.y << 32) | (ull)hpk.x;
      int jg = (j0 & 127) >> 2;
      __hip_atomic_store(exch + ((((size_t)(lstm*2 + bufi)*2 + half)*16 + b)*32 + jg),
                         val, __ATOMIC_RELAXED, __HIP_MEMORY_SCOPE_AGENT);
      if (l == 0)
        __hip_atomic_fetch_add(myctr, 1, __ATOMIC_RELEASE, __HIP_MEMORY_SCOPE_AGENT);
      // wait for partner half
      const int want = 8*(t + 1);
      while (__hip_atomic_load(pctr, __ATOMIC_ACQUIRE, __HIP_MEMORY_SCOPE_AGENT) < want) {}
      int pb = tid >> 5, pj = tid & 31;
      ull pv = __hip_atomic_load(exch + ((((size_t)(lstm*2 + bufi)*2 + (half^1))*16 + pb)*32 + pj),
                                 __ATOMIC_RELAXED, __HIP_MEMORY_SCOPE_AGENT);
      uint2 pk2; pk2.x = (unsigned)pv; pk2.y = (unsigned)(pv >> 32);
      *(uint2*)(nxt + ((pb*768 + 256*(half^1) + 8*pj) ^ ((unsigned)(pb & 7) << 4))) = pk2;
    }
    if (ldx) *(uint2*)(nxt + ((tid*768 + 512) ^ ((unsigned)(tid & 7) << 4))) = gx;
    __syncthreads();
  }
}

// ---------------------------------------------------------------------------
// enc_out[t,b,k] = enc_h[k,t,b,:] . enc_outW[k,:] + enc_outb[k]
// ---------------------------------------------------------------------------
__global__ __launch_bounds__(256) void k_encout(
    const unsigned short* __restrict__ enc_h, const float* __restrict__ outW,
    const float* __restrict__ outb, float* __restrict__ enc_out_tb)
{
  const int l = threadIdx.x & 63;
  const int wid = (blockIdx.x*blockDim.x + threadIdx.x) >> 6;
  const int nw = (gridDim.x*blockDim.x) >> 6;
  for (int e = wid; e < 3*1024*16; e += nw){
    int k = e >> 14;
    int t = (e >> 4) & 1023;
    int b = e & 15;
    uint2 v = *(const uint2*)(enc_h + ((size_t)(k*1024 + t)*16 + b)*256 + 4*l);
    float p = bf2f(v.x & 0xffff)*outW[k*256 + 4*l]
            + bf2f(v.x >> 16)   *outW[k*256 + 4*l + 1]
            + bf2f(v.y & 0xffff)*outW[k*256 + 4*l + 2]
            + bf2f(v.y >> 16)   *outW[k*256 + 4*l + 3];
    #pragma unroll
    for (int s = 1; s < 64; s <<= 1) p += __shfl_xor(p, s);
    if (l == 0) enc_out_tb[(t*16 + b)*3 + k] = p + outb[k];
  }
}

// ---------------------------------------------------------------------------
// y[b,t] = relu(dec_h[t,b,:] @ W1 + b1) @ W2 + b2
// ---------------------------------------------------------------------------
__global__ __launch_bounds__(256) void k_decout(
    const unsigned short* __restrict__ dec_h, const float* __restrict__ W1,
    const float* __restrict__ b1, const float* __restrict__ W2,
    const float* __restrict__ b2, float* __restrict__ out)
{
  const int l = threadIdx.x & 63;
  const int wid = (blockIdx.x*blockDim.x + threadIdx.x) >> 6;
  const int nw = (gridDim.x*blockDim.x) >> 6;
  const int o = l >> 4, jc = l & 15;
  for (int e = wid; e < 16384; e += nw){
    int t = e >> 4, b = e & 15;
    const unsigned short* hr = dec_h + (size_t)(t*16 + b)*256 + jc*16;
    uint4 v0 = *(const uint4*)hr;
    uint4 v1 = *(const uint4*)(hr + 8);
    unsigned vv[8] = {v0.x, v0.y, v0.z, v0.w, v1.x, v1.y, v1.z, v1.w};
    float p = 0.f;
    #pragma unroll
    for (int q = 0; q < 8; ++q){
      int j = jc*16 + 2*q;
      p += bf2f(vv[q] & 0xffff) * W1[j*4 + o];
      p += bf2f(vv[q] >> 16)    * W1[(j + 1)*4 + o];
    }
    p += __shfl_xor(p, 1); p += __shfl_xor(p, 2);
    p += __shfl_xor(p, 4); p += __shfl_xor(p, 8);
    float v = 0.f;
    if (jc == 0) v = fmaxf(p + b1[o], 0.f) * W2[o];
    v += __shfl_xor(v, 16);
    v += __shfl_xor(v, 32);
    if (l == 0) out[b*1024 + t] = v + b2[0];
  }
}

// ---------------------------------------------------------------------------
extern "C" void kernel_launch(void* const* d_in, const int* in_sizes, int n_in,
                              void* d_out, int out_size, void* d_ws, size_t ws_size,
                              hipStream_t stream)
{
  const float* faceF   = (const float*)d_in[1];
  const float* audioF  = (const float*)d_in[2];
  const float* textF   = (const float*)d_in[3];
  const float* target  = (const float*)d_in[4];
  const float* textW   = (const float*)d_in[5];
  const float* textB   = (const float*)d_in[6];
  const float* faceW   = (const float*)d_in[7];
  const float* faceB   = (const float*)d_in[8];
  const float* audioW  = (const float*)d_in[9];
  const float* audioB  = (const float*)d_in[10];
  const float* attW    = (const float*)d_in[11];
  const float* utW     = (const float*)d_in[13];
  const float* ufW     = (const float*)d_in[15];
  const float* uaW     = (const float*)d_in[17];
  const float* encWih  = (const float*)d_in[19];
  const float* encWhh  = (const float*)d_in[20];
  const float* encB    = (const float*)d_in[21];
  const float* encOutW = (const float*)d_in[22];
  const float* encOutB = (const float*)d_in[23];
  const float* decWih  = (const float*)d_in[24];
  const float* decWhh  = (const float*)d_in[25];
  const float* decB    = (const float*)d_in[26];
  const float* decH0   = (const float*)d_in[27];
  const float* decC0   = (const float*)d_in[28];
  const float* out1W   = (const float*)d_in[29];
  const float* out1B   = (const float*)d_in[30];
  const float* out2W   = (const float*)d_in[31];
  const float* out2B   = (const float*)d_in[32];
  float* out = (float*)d_out;

  char* ws = (char*)d_ws;
  size_t off = 0;
  auto alloc = [&](size_t bytes) -> void* {
    void* p = ws + off;
    off += (bytes + 255) & ~(size_t)255;
    return p;
  };
  unsigned short* packL   = (unsigned short*)alloc(1179648ull*2);
  unsigned short* packT   = (unsigned short*)alloc(196608ull*2);
  unsigned short* packF   = (unsigned short*)alloc(131072ull*2);
  unsigned short* packA   = (unsigned short*)alloc(65536ull*2);
  unsigned short* tanhT   = (unsigned short*)alloc(16384ull*256*2);
  unsigned short* tanhF   = (unsigned short*)alloc(16384ull*256*2);
  unsigned short* tanhA   = (unsigned short*)alloc(16384ull*256*2);
  float*          s6      = (float*)alloc(6ull*16384*4);
  float*          attn_tb = (float*)alloc(49152ull*4);
  unsigned short* encfeed = (unsigned short*)alloc(65536ull*2);
  unsigned short* decfeed = (unsigned short*)alloc(65536ull*2);
  unsigned short* enc_h   = (unsigned short*)alloc(3ull*1024*16*256*2);
  float*          enc_out_tb = (float*)alloc(49152ull*4);
  unsigned short* dec_h   = (unsigned short*)alloc(1024ull*16*256*2);
  ull*            exch    = (ull*)alloc(8192ull*8);
  int*            ctr     = (int*)alloc(64);
  if (off > ws_size) return;

  hipLaunchKernelGGL(k_pack_lstm, dim3(512), dim3(256), 0, stream,
                     encWhh, encWih, decWhh, decWih, encB, decB, packL);
  hipLaunchKernelGGL(k_pack_B, dim3(256), dim3(256), 0, stream, textW, 24, packT);
  hipLaunchKernelGGL(k_pack_B, dim3(256), dim3(256), 0, stream, faceW, 16, packF);
  hipLaunchKernelGGL(k_pack_B, dim3(128), dim3(256), 0, stream, audioW, 8, packA);

  hipLaunchKernelGGL(k_proj, dim3(128, 2), dim3(256), 0, stream, textF,  packT, textB,  tanhT, 768);
  hipLaunchKernelGGL(k_proj, dim3(128, 2), dim3(256), 0, stream, faceF,  packF, faceB,  tanhF, 512);
  hipLaunchKernelGGL(k_proj, dim3(128, 2), dim3(256), 0, stream, audioF, packA, audioB, tanhA, 256);

  hipLaunchKernelGGL(k_attdot, dim3(256), dim3(256), 0, stream,
                     tanhT, tanhF, tanhA, attW, utW, ufW, uaW, s6);
  hipLaunchKernelGGL(k_zerofeed, dim3(64), dim3(256), 0, stream, encfeed, ctr);
  hipLaunchKernelGGL(k_smax, dim3(96), dim3(256), 0, stream, s6, attn_tb, encfeed);

  // encoder: 3 LSTMs x 2 half-blocks
  hipLaunchKernelGGL(k_lstm, dim3(6), dim3(512), 0, stream,
                     packL, encfeed, decfeed, decH0, decC0,
                     enc_h, dec_h, exch, ctr, 0);
  hipLaunchKernelGGL(k_encout, dim3(256), dim3(256), 0, stream,
                     enc_h, encOutW, encOutB, enc_out_tb);
  hipLaunchKernelGGL(k_ctx, dim3(64), dim3(256), 0, stream,
                     attn_tb, enc_out_tb, target, decfeed);
  // decoder: 1 LSTM x 2 half-blocks
  hipLaunchKernelGGL(k_lstm, dim3(2), dim3(512), 0, stream,
                     packL, encfeed, decfeed, decH0, decC0,
                     enc_h, dec_h, exch, ctr, 3);
  hipLaunchKernelGGL(k_decout, dim3(256), dim3(256), 0, stream,
                     dec_h, out1W, out1B, out2W, out2B, out);
}

// Round 4
// 8728.426 us; speedup vs baseline: 3.0571x; 2.2881x over previous
//
#include <hip/hip_runtime.h>
#include <hip/hip_bf16.h>

typedef float f32x4 __attribute__((ext_vector_type(4)));
typedef __bf16 bf16x8 __attribute__((ext_vector_type(8)));
typedef unsigned long long ull;

#define DEVI static __device__ __forceinline__

DEVI unsigned f2bfu(float f){
  unsigned u = __builtin_bit_cast(unsigned, f);
  return (u + 0x7fffu + ((u >> 16) & 1u)) >> 16;   // RNE f32->bf16
}
DEVI float bf2f(unsigned s){
  return __builtin_bit_cast(float, s << 16);
}
DEVI float sigf(float x){ return 1.f/(1.f + __expf(-x)); }
DEVI float thf(float x){ return 2.f*sigf(2.f*x) - 1.f; }

// ---------------------------------------------------------------------------
// Pack LSTM weights (4 LSTMs) into A-fragment-linear bf16 layout.
// W_aug is (288 x 1024): rows 0..255 = Whh, rows 256+ = Wih, row 260 = bias
// (consumed by a constant-1.0 input row), rest 0.
// frag (lstm, wglob(0..15), kt(0..8), g(0..3)); element (lane, j):
//   value = W_aug[32*kt + 8*(l>>4) + j][256*g + 16*wglob + (l&15)]
// ---------------------------------------------------------------------------
__global__ __launch_bounds__(256) void k_pack_lstm(
    const float* __restrict__ encWhh, const float* __restrict__ encWih,
    const float* __restrict__ decWhh, const float* __restrict__ decWih,
    const float* __restrict__ encB,   const float* __restrict__ decB,
    unsigned short* __restrict__ outp)
{
  const int total = 4*16*9*4*64*8;
  for (int e = blockIdx.x*blockDim.x + threadIdx.x; e < total; e += gridDim.x*blockDim.x){
    int j  = e & 7;
    int l  = (e >> 3) & 63;
    int g  = (e >> 9) & 3;
    int r  = e >> 11;          // (lstm*16 + w)*9 + kt
    int kt = r % 9;  r /= 9;
    int w  = r & 15;
    int lstm = r >> 4;
    int k = 32*kt + 8*(l >> 4) + j;
    int n = 256*g + 16*w + (l & 15);
    float v = 0.f;
    if (lstm < 3){
      if (k < 256)       v = encWhh[(lstm*256 + k)*1024 + n];
      else if (k < 259)  v = encWih[(lstm*3 + (k-256))*1024 + n];
      else if (k == 260) v = encB[lstm*1024 + n];
    } else {
      if (k < 256)       v = decWhh[k*1024 + n];
      else if (k < 260)  v = decWih[(k-256)*1024 + n];
      else if (k == 260) v = decB[n];
    }
    outp[e] = (unsigned short)f2bfu(v);
  }
}

// ---------------------------------------------------------------------------
// Pack projection weights (K x 256 f32) into B-fragment-linear bf16.
// ---------------------------------------------------------------------------
__global__ __launch_bounds__(256) void k_pack_B(
    const float* __restrict__ W, int KT, unsigned short* __restrict__ outp)
{
  const int total = 2*KT*8*64*8;
  for (int e = blockIdx.x*blockDim.x + threadIdx.x; e < total; e += gridDim.x*blockDim.x){
    int j  = e & 7;
    int l  = (e >> 3) & 63;
    int nt = (e >> 9) & 7;
    int r  = e >> 12;          // tn*KT + kt
    int kt = r % KT;
    int tn = r / KT;
    int k = 32*kt + 8*(l >> 4) + j;
    int n = 128*tn + 16*nt + (l & 15);
    outp[e] = (unsigned short)f2bfu(W[k*256 + n]);
  }
}

// ---------------------------------------------------------------------------
// Projection GEMM: C = A(16384xK) * B(Kx256) + bias, then tanh -> bf16 buffer.
// ---------------------------------------------------------------------------
__global__ __launch_bounds__(256) void k_proj(
    const float* __restrict__ A, const unsigned short* __restrict__ Bp,
    const float* __restrict__ bias, unsigned short* __restrict__ outT, int K)
{
  __shared__ unsigned char sA[8192];
  __shared__ unsigned char sB[8192];
  const int tid = threadIdx.x;
  const int l = tid & 63;
  const int wv = tid >> 6;
  const int wm = wv >> 1, wn = wv & 1;
  const int tm = blockIdx.x, tn = blockIdx.y;
  const int KT = K >> 5;

  f32x4 acc[4][4];
  #pragma unroll
  for (int a = 0; a < 4; ++a)
    #pragma unroll
    for (int cc = 0; cc < 4; ++cc)
      acc[a][cc] = f32x4{0.f,0.f,0.f,0.f};

  const int arow = tid >> 1;
  const float* Ap = A + (size_t)(tm*128 + arow)*K + (tid & 1)*16;
  const uint4* Bsrc = (const uint4*)Bp + (size_t)tn*KT*512 + tid*2;

  for (int kt = 0; kt < KT; ++kt){
    float4 f0 = *(const float4*)(Ap + kt*32);
    float4 f1 = *(const float4*)(Ap + kt*32 + 4);
    float4 f2 = *(const float4*)(Ap + kt*32 + 8);
    float4 f3 = *(const float4*)(Ap + kt*32 + 12);
    uint4 p0, p1;
    p0.x = f2bfu(f0.x) | (f2bfu(f0.y) << 16);
    p0.y = f2bfu(f0.z) | (f2bfu(f0.w) << 16);
    p0.z = f2bfu(f1.x) | (f2bfu(f1.y) << 16);
    p0.w = f2bfu(f1.z) | (f2bfu(f1.w) << 16);
    p1.x = f2bfu(f2.x) | (f2bfu(f2.y) << 16);
    p1.y = f2bfu(f2.z) | (f2bfu(f2.w) << 16);
    p1.z = f2bfu(f3.x) | (f2bfu(f3.y) << 16);
    p1.w = f2bfu(f3.z) | (f2bfu(f3.w) << 16);
    unsigned base = arow*64 + (tid & 1)*32;
    unsigned sw = (arow & 3) << 4;
    *(uint4*)(sA + ((base)      ^ sw)) = p0;
    *(uint4*)(sA + ((base + 16) ^ sw)) = p1;
    *((uint4*)sB + tid*2)     = Bsrc[kt*512];
    *((uint4*)sB + tid*2 + 1) = Bsrc[kt*512 + 1];
    __syncthreads();

    bf16x8 af[4], bf[4];
    #pragma unroll
    for (int a = 0; a < 4; ++a){
      unsigned row = 64*wm + 16*a + (l & 15);
      unsigned off = (row*64 + 16*(l >> 4)) ^ ((row & 3) << 4);
      af[a] = __builtin_bit_cast(bf16x8, *(const uint4*)(sA + off));
    }
    #pragma unroll
    for (int cc = 0; cc < 4; ++cc){
      unsigned off = ((4*wn + cc)*64 + l)*16;
      bf[cc] = __builtin_bit_cast(bf16x8, *(const uint4*)(sB + off));
    }
    #pragma unroll
    for (int a = 0; a < 4; ++a)
      #pragma unroll
      for (int cc = 0; cc < 4; ++cc)
        acc[a][cc] = __builtin_amdgcn_mfma_f32_16x16x32_bf16(af[a], bf[cc], acc[a][cc], 0, 0, 0);
    __syncthreads();
  }
  #pragma unroll
  for (int cc = 0; cc < 4; ++cc){
    int colg = tn*128 + 64*wn + 16*cc + (l & 15);
    float bs = bias[colg];
    #pragma unroll
    for (int a = 0; a < 4; ++a){
      int rowg = tm*128 + 64*wm + 16*a + 4*(l >> 4);
      #pragma unroll
      for (int r = 0; r < 4; ++r){
        outT[(size_t)(rowg + r)*256 + colg] = (unsigned short)f2bfu(thf(acc[a][cc][r] + bs));
      }
    }
  }
}

// ---------------------------------------------------------------------------
// Attention scalar dots. 7 partial dots -> 6 score fields (6,B,T) f32.
// ---------------------------------------------------------------------------
__global__ __launch_bounds__(256) void k_attdot(
    const unsigned short* __restrict__ tT, const unsigned short* __restrict__ tF,
    const unsigned short* __restrict__ tA,
    const float* __restrict__ attW, const float* __restrict__ utW,
    const float* __restrict__ ufW, const float* __restrict__ uaW,
    float* __restrict__ s6)
{
  const int l = threadIdx.x & 63;
  const int wid = (blockIdx.x*blockDim.x + threadIdx.x) >> 6;
  const int nw = (gridDim.x*blockDim.x) >> 6;
  float alo[4], ahi[4], wt[4], wf[4], wa[4];
  #pragma unroll
  for (int q = 0; q < 4; ++q){
    alo[q] = attW[4*l + q];
    ahi[q] = attW[256 + 4*l + q];
    wt[q]  = utW[4*l + q];
    wf[q]  = ufW[4*l + q];
    wa[q]  = uaW[4*l + q];
  }
  for (int r = wid; r < 16384; r += nw){
    uint2 vT = *(const uint2*)(tT + (size_t)r*256 + 4*l);
    uint2 vF = *(const uint2*)(tF + (size_t)r*256 + 4*l);
    uint2 vA = *(const uint2*)(tA + (size_t)r*256 + 4*l);
    float xt[4] = { bf2f(vT.x & 0xffff), bf2f(vT.x >> 16), bf2f(vT.y & 0xffff), bf2f(vT.y >> 16) };
    float xf[4] = { bf2f(vF.x & 0xffff), bf2f(vF.x >> 16), bf2f(vF.y & 0xffff), bf2f(vF.y >> 16) };
    float xa[4] = { bf2f(vA.x & 0xffff), bf2f(vA.x >> 16), bf2f(vA.y & 0xffff), bf2f(vA.y >> 16) };
    float ptlo = 0.f, ptu = 0.f, pflo = 0.f, pfhi = 0.f, pfu = 0.f, pahi = 0.f, pau = 0.f;
    #pragma unroll
    for (int q = 0; q < 4; ++q){
      ptlo += xt[q]*alo[q]; ptu += xt[q]*wt[q];
      pflo += xf[q]*alo[q]; pfhi += xf[q]*ahi[q]; pfu += xf[q]*wf[q];
      pahi += xa[q]*ahi[q]; pau += xa[q]*wa[q];
    }
    #pragma unroll
    for (int s = 1; s < 64; s <<= 1){
      ptlo += __shfl_xor(ptlo, s); ptu  += __shfl_xor(ptu, s);
      pflo += __shfl_xor(pflo, s); pfhi += __shfl_xor(pfhi, s);
      pfu  += __shfl_xor(pfu, s);  pahi += __shfl_xor(pahi, s);
      pau  += __shfl_xor(pau, s);
    }
    if (l == 0){
      int o = r;
      s6[o]             = ptlo + pfhi;
      s6[16384 + o]     = pflo + pahi;
      s6[2*16384 + o]   = ptlo + pahi;
      s6[3*16384 + o]   = ptu;
      s6[4*16384 + o]   = pfu;
      s6[5*16384 + o]   = pau;
    }
  }
}

// ---------------------------------------------------------------------------
__global__ __launch_bounds__(256) void k_zerofeed(unsigned short* __restrict__ encfeed,
                                                  int* __restrict__ ctr)
{
  int i = blockIdx.x*blockDim.x + threadIdx.x;
  if (i < 16384) encfeed[i*4 + 3] = 0;
  if (i < 8) ctr[i] = 0;
}

// ---------------------------------------------------------------------------
// Softmax over T per (field,b). Fields 0..2 -> attn_tb f32; 3..5 -> encfeed bf16.
// ---------------------------------------------------------------------------
__global__ __launch_bounds__(256) void k_smax(
    const float* __restrict__ s6, float* __restrict__ attn_tb,
    unsigned short* __restrict__ encfeed)
{
  __shared__ float red[4];
  const int f = blockIdx.x >> 4;
  const int b = blockIdx.x & 15;
  const int tid = threadIdx.x;
  const float* row = s6 + f*16384 + b*1024;
  float4 v = *(const float4*)(row + 4*tid);
  float mx = fmaxf(fmaxf(v.x, v.y), fmaxf(v.z, v.w));
  #pragma unroll
  for (int s = 1; s < 64; s <<= 1) mx = fmaxf(mx, __shfl_xor(mx, s));
  if ((tid & 63) == 0) red[tid >> 6] = mx;
  __syncthreads();
  mx = fmaxf(fmaxf(red[0], red[1]), fmaxf(red[2], red[3]));
  float e0 = __expf(v.x - mx), e1 = __expf(v.y - mx), e2 = __expf(v.z - mx), e3 = __expf(v.w - mx);
  float sm = e0 + e1 + e2 + e3;
  __syncthreads();
  #pragma unroll
  for (int s = 1; s < 64; s <<= 1) sm += __shfl_xor(sm, s);
  if ((tid & 63) == 0) red[tid >> 6] = sm;
  __syncthreads();
  sm = red[0] + red[1] + red[2] + red[3];
  float inv = 1.f/sm;
  float e[4] = {e0, e1, e2, e3};
  int ff = (f < 3) ? f : f - 3;
  #pragma unroll
  for (int q = 0; q < 4; ++q){
    int idx = ff*1024 + 4*tid + q;
    int tt = idx/3, kk = idx - 3*tt;
    if (f < 3) attn_tb[(tt*16 + b)*3 + kk] = e[q]*inv;
    else       encfeed[(tt*16 + b)*4 + kk] = (unsigned short)f2bfu(e[q]*inv);
  }
}

// ---------------------------------------------------------------------------
// Decoder feed: decfeed[t,b,0] = shifted target; [t,b,1+k] = context(t,b,k)
// ---------------------------------------------------------------------------
__global__ __launch_bounds__(256) void k_ctx(
    const float* __restrict__ attn_tb, const float* __restrict__ enc_out_tb,
    const float* __restrict__ target, unsigned short* __restrict__ decfeed)
{
  int i = blockIdx.x*blockDim.x + threadIdx.x;   // t*16 + b
  if (i >= 16384) return;
  int t = i >> 4, b = i & 15;
  float a0 = attn_tb[i*3], a1 = attn_tb[i*3+1], a2 = attn_tb[i*3+2];
  unsigned o[4];
  o[0] = f2bfu(t > 0 ? target[b*1024 + t - 1] : 0.f);
  #pragma unroll
  for (int k = 0; k < 3; ++k){
    float s = a0 * enc_out_tb[i*3 + k];
    if (t >= 1) s += a1 * enc_out_tb[(i-16)*3 + k];
    if (t >= 2) s += a2 * enc_out_tb[(i-32)*3 + k];
    o[k+1] = f2bfu(s);
  }
  uint2 pk; pk.x = o[0] | (o[1] << 16); pk.y = o[2] | (o[3] << 16);
  *(uint2*)(decfeed + (size_t)i*4) = pk;
}

// ---------------------------------------------------------------------------
// LSTM recurrence, 2 blocks (CUs) per LSTM, 512 threads = 8 waves each.
// Block `half` owns h-cols [128*half, 128*half+128); wave w owns 16 cols.
// Weights register-resident: 36 frags = 144 VGPR/wave, pinned via asm so the
// compiler cannot sink the loads back into the loop (round-3 failure mode).
// Halves exchange h through LLC: per-wave release atomicAdd (wave's vmcnt
// drains first), a SINGLE poller thread, barrier broadcast.
// Bias enters via constant-1.0 input row (k=260). Two barriers per step.
// ---------------------------------------------------------------------------
__global__ __launch_bounds__(512, 2) void k_lstm(
    const unsigned short* __restrict__ packW,
    const unsigned short* __restrict__ encfeed,
    const unsigned short* __restrict__ decfeed,
    const float* __restrict__ dec_h0,
    const float* __restrict__ dec_c0,
    unsigned short* __restrict__ enc_h,
    unsigned short* __restrict__ dec_h,
    ull* __restrict__ exch,
    int* __restrict__ ctr,
    int lstm0)
{
  __shared__ unsigned char hl[2][16*768];   // bf16 [b][k 0..287], row 768B, XOR swizzle
  const int tid = threadIdx.x;
  const int l = tid & 63;
  const int w = tid >> 6;                   // 0..7
  const int lstm = lstm0 + (blockIdx.x >> 1);
  const int half = blockIdx.x & 1;
  const int wglob = half*8 + w;             // 0..15
  const bool isdec = (lstm == 3);
  const unsigned short* feed = isdec ? decfeed : encfeed;
  unsigned short* hout = isdec ? dec_h : (enc_h + (size_t)lstm*1024*16*256);

  const int b = l & 15;
  const int j0 = 16*wglob + 4*(l >> 4);
  const unsigned swb = (unsigned)(b & 7) << 4;

  float c[4];
  #pragma unroll
  for (int r = 0; r < 4; ++r) c[r] = isdec ? dec_c0[j0 + r] : 0.f;

  // full h(0) into buf0 (both halves): 512 threads x 2 uint2 = 256 cols x 16 b
  {
    int ib = tid >> 5;
    int ic = (tid & 31) * 8;
    #pragma unroll
    for (int q = 0; q < 2; ++q){
      int c0 = ic + 4*q;
      uint2 hz;
      if (isdec){
        hz.x = f2bfu(dec_h0[c0])   | (f2bfu(dec_h0[c0+1]) << 16);
        hz.y = f2bfu(dec_h0[c0+2]) | (f2bfu(dec_h0[c0+3]) << 16);
      } else { hz.x = 0u; hz.y = 0u; }
      *(uint2*)(hl[0] + ((ib*768 + 2*c0) ^ ((unsigned)(ib & 7) << 4))) = hz;
    }
  }
  // rows 260..287 in both buffers: row 260 = 1.0 (bias row), rest 0
  if (tid < 224){
    int bufi = tid / 112;
    int r = tid % 112;
    int bb = r / 7, q = r % 7;
    uint2 z;
    z.x = (q == 0) ? 0x00003f80u : 0u;  // col260=1.0 bf16, col261=0
    z.y = 0u;
    *(uint2*)(hl[bufi] + ((bb*768 + 520 + 8*q) ^ ((unsigned)(bb & 7) << 4))) = z;
  }
  // x(0) rows 256..259 into buf0
  if (tid < 16){
    uint2 gx0 = *(const uint2*)(feed + tid*4);
    *(uint2*)(hl[0] + ((tid*768 + 512) ^ ((unsigned)(tid & 7) << 4))) = gx0;
  }

  // preload 36 weight fragments into registers (144 VGPRs) and PIN them:
  // the empty asm makes each value opaque so the loads cannot be sunk or
  // rematerialized inside the t-loop.
  const uint4* wb = (const uint4*)packW + ((size_t)(lstm*16 + wglob)*36)*64 + l;
  uint4 wreg[36];
  #pragma unroll
  for (int i = 0; i < 36; ++i) wreg[i] = wb[i*64];
  #pragma unroll
  for (int i = 0; i < 36; ++i)
    asm volatile("" : "+v"(wreg[i].x), "+v"(wreg[i].y), "+v"(wreg[i].z), "+v"(wreg[i].w));

  int* myctr = ctr + lstm*2 + half;
  int* pctr  = ctr + lstm*2 + (half^1);

  __syncthreads();

  for (int t = 0; t < 1024; ++t){
    const unsigned char* cur = hl[t & 1];
    unsigned char* nxt = (unsigned char*)hl[(t + 1) & 1];

    // B-frags: h_aug for this batch column
    bf16x8 af[9];
    #pragma unroll
    for (int kt = 0; kt < 9; ++kt){
      unsigned off = (unsigned)(b*768 + kt*64 + 16*(l >> 4)) ^ swb;
      af[kt] = __builtin_bit_cast(bf16x8, *(const uint4*)(cur + off));
    }

    // prefetch x(t+1)
    uint2 gx;
    const bool ldx = (t < 1023) && (tid < 16);
    if (ldx) gx = *(const uint2*)(feed + (size_t)(t + 1)*64 + tid*4);

    f32x4 acc[4];
    #pragma unroll
    for (int g = 0; g < 4; ++g) acc[g] = f32x4{0.f,0.f,0.f,0.f};
    #pragma unroll
    for (int kt = 0; kt < 9; ++kt){
      #pragma unroll
      for (int g = 0; g < 4; ++g)
        acc[g] = __builtin_amdgcn_mfma_f32_16x16x32_bf16(
            __builtin_bit_cast(bf16x8, wreg[kt*4 + g]), af[kt], acc[g], 0, 0, 0);
    }

    // cell epilogue fully in registers (bias already in acc via k=260 row)
    unsigned hp[4];
    #pragma unroll
    for (int r = 0; r < 4; ++r){
      float vi = sigf(acc[0][r]);
      float vf = sigf(acc[1][r]);
      float vg = thf (acc[2][r]);
      float vo = sigf(acc[3][r]);
      float cc = vf*c[r] + vi*vg;
      c[r] = cc;
      hp[r] = f2bfu(vo * thf(cc));
    }
    uint2 hpk; hpk.x = hp[0] | (hp[1] << 16); hpk.y = hp[2] | (hp[3] << 16);
    *(uint2*)(nxt + ((b*768 + 2*j0) ^ swb)) = hpk;
    *(uint2*)(hout + (size_t)(t*16 + b)*256 + j0) = hpk;

    if (t < 1023){
      const int bufi = (t + 1) & 1;
      // publish own half to LLC
      ull val = ((ull)hpk.y << 32) | (ull)hpk.x;
      int jg = (j0 & 127) >> 2;
      __hip_atomic_store(exch + ((((size_t)(lstm*2 + bufi)*2 + half)*16 + b)*32 + jg),
                         val, __ATOMIC_RELAXED, __HIP_MEMORY_SCOPE_AGENT);
      if (l == 0)
        __hip_atomic_fetch_add(myctr, 1, __ATOMIC_RELEASE, __HIP_MEMORY_SCOPE_AGENT);
      // single poller waits for partner half, barrier broadcasts
      if (tid == 0){
        const int want = 8*(t + 1);
        while (__hip_atomic_load(pctr, __ATOMIC_ACQUIRE, __HIP_MEMORY_SCOPE_AGENT) < want) {}
      }
      __syncthreads();
      int pb = tid >> 5, pj = tid & 31;
      ull pv = __hip_atomic_load(exch + ((((size_t)(lstm*2 + bufi)*2 + (half^1))*16 + pb)*32 + pj),
                                 __ATOMIC_RELAXED, __HIP_MEMORY_SCOPE_AGENT);
      uint2 pk2; pk2.x = (unsigned)pv; pk2.y = (unsigned)(pv >> 32);
      *(uint2*)(nxt + ((pb*768 + 256*(half^1) + 8*pj) ^ ((unsigned)(pb & 7) << 4))) = pk2;
      if (ldx) *(uint2*)(nxt + ((tid*768 + 512) ^ ((unsigned)(tid & 7) << 4))) = gx;
      __syncthreads();
    }
  }
}

// ---------------------------------------------------------------------------
// enc_out[t,b,k] = enc_h[k,t,b,:] . enc_outW[k,:] + enc_outb[k]
// ---------------------------------------------------------------------------
__global__ __launch_bounds__(256) void k_encout(
    const unsigned short* __restrict__ enc_h, const float* __restrict__ outW,
    const float* __restrict__ outb, float* __restrict__ enc_out_tb)
{
  const int l = threadIdx.x & 63;
  const int wid = (blockIdx.x*blockDim.x + threadIdx.x) >> 6;
  const int nw = (gridDim.x*blockDim.x) >> 6;
  for (int e = wid; e < 3*1024*16; e += nw){
    int k = e >> 14;
    int t = (e >> 4) & 1023;
    int b = e & 15;
    uint2 v = *(const uint2*)(enc_h + ((size_t)(k*1024 + t)*16 + b)*256 + 4*l);
    float p = bf2f(v.x & 0xffff)*outW[k*256 + 4*l]
            + bf2f(v.x >> 16)   *outW[k*256 + 4*l + 1]
            + bf2f(v.y & 0xffff)*outW[k*256 + 4*l + 2]
            + bf2f(v.y >> 16)   *outW[k*256 + 4*l + 3];
    #pragma unroll
    for (int s = 1; s < 64; s <<= 1) p += __shfl_xor(p, s);
    if (l == 0) enc_out_tb[(t*16 + b)*3 + k] = p + outb[k];
  }
}

// ---------------------------------------------------------------------------
// y[b,t] = relu(dec_h[t,b,:] @ W1 + b1) @ W2 + b2
// ---------------------------------------------------------------------------
__global__ __launch_bounds__(256) void k_decout(
    const unsigned short* __restrict__ dec_h, const float* __restrict__ W1,
    const float* __restrict__ b1, const float* __restrict__ W2,
    const float* __restrict__ b2, float* __restrict__ out)
{
  const int l = threadIdx.x & 63;
  const int wid = (blockIdx.x*blockDim.x + threadIdx.x) >> 6;
  const int nw = (gridDim.x*blockDim.x) >> 6;
  const int o = l >> 4, jc = l & 15;
  for (int e = wid; e < 16384; e += nw){
    int t = e >> 4, b = e & 15;
    const unsigned short* hr = dec_h + (size_t)(t*16 + b)*256 + jc*16;
    uint4 v0 = *(const uint4*)hr;
    uint4 v1 = *(const uint4*)(hr + 8);
    unsigned vv[8] = {v0.x, v0.y, v0.z, v0.w, v1.x, v1.y, v1.z, v1.w};
    float p = 0.f;
    #pragma unroll
    for (int q = 0; q < 8; ++q){
      int j = jc*16 + 2*q;
      p += bf2f(vv[q] & 0xffff) * W1[j*4 + o];
      p += bf2f(vv[q] >> 16)    * W1[(j + 1)*4 + o];
    }
    p += __shfl_xor(p, 1); p += __shfl_xor(p, 2);
    p += __shfl_xor(p, 4); p += __shfl_xor(p, 8);
    float v = 0.f;
    if (jc == 0) v = fmaxf(p + b1[o], 0.f) * W2[o];
    v += __shfl_xor(v, 16);
    v += __shfl_xor(v, 32);
    if (l == 0) out[b*1024 + t] = v + b2[0];
  }
}

// ---------------------------------------------------------------------------
extern "C" void kernel_launch(void* const* d_in, const int* in_sizes, int n_in,
                              void* d_out, int out_size, void* d_ws, size_t ws_size,
                              hipStream_t stream)
{
  const float* faceF   = (const float*)d_in[1];
  const float* audioF  = (const float*)d_in[2];
  const float* textF   = (const float*)d_in[3];
  const float* target  = (const float*)d_in[4];
  const float* textW   = (const float*)d_in[5];
  const float* textB   = (const float*)d_in[6];
  const float* faceW   = (const float*)d_in[7];
  const float* faceB   = (const float*)d_in[8];
  const float* audioW  = (const float*)d_in[9];
  const float* audioB  = (const float*)d_in[10];
  const float* attW    = (const float*)d_in[11];
  const float* utW     = (const float*)d_in[13];
  const float* ufW     = (const float*)d_in[15];
  const float* uaW     = (const float*)d_in[17];
  const float* encWih  = (const float*)d_in[19];
  const float* encWhh  = (const float*)d_in[20];
  const float* encB    = (const float*)d_in[21];
  const float* encOutW = (const float*)d_in[22];
  const float* encOutB = (const float*)d_in[23];
  const float* decWih  = (const float*)d_in[24];
  const float* decWhh  = (const float*)d_in[25];
  const float* decB    = (const float*)d_in[26];
  const float* decH0   = (const float*)d_in[27];
  const float* decC0   = (const float*)d_in[28];
  const float* out1W   = (const float*)d_in[29];
  const float* out1B   = (const float*)d_in[30];
  const float* out2W   = (const float*)d_in[31];
  const float* out2B   = (const float*)d_in[32];
  float* out = (float*)d_out;

  char* ws = (char*)d_ws;
  size_t off = 0;
  auto alloc = [&](size_t bytes) -> void* {
    void* p = ws + off;
    off += (bytes + 255) & ~(size_t)255;
    return p;
  };
  unsigned short* packL   = (unsigned short*)alloc(1179648ull*2);
  unsigned short* packT   = (unsigned short*)alloc(196608ull*2);
  unsigned short* packF   = (unsigned short*)alloc(131072ull*2);
  unsigned short* packA   = (unsigned short*)alloc(65536ull*2);
  unsigned short* tanhT   = (unsigned short*)alloc(16384ull*256*2);
  unsigned short* tanhF   = (unsigned short*)alloc(16384ull*256*2);
  unsigned short* tanhA   = (unsigned short*)alloc(16384ull*256*2);
  float*          s6      = (float*)alloc(6ull*16384*4);
  float*          attn_tb = (float*)alloc(49152ull*4);
  unsigned short* encfeed = (unsigned short*)alloc(65536ull*2);
  unsigned short* decfeed = (unsigned short*)alloc(65536ull*2);
  unsigned short* enc_h   = (unsigned short*)alloc(3ull*1024*16*256*2);
  float*          enc_out_tb = (float*)alloc(49152ull*4);
  unsigned short* dec_h   = (unsigned short*)alloc(1024ull*16*256*2);
  ull*            exch    = (ull*)alloc(8192ull*8);
  int*            ctr     = (int*)alloc(64);
  if (off > ws_size) return;

  hipLaunchKernelGGL(k_pack_lstm, dim3(512), dim3(256), 0, stream,
                     encWhh, encWih, decWhh, decWih, encB, decB, packL);
  hipLaunchKernelGGL(k_pack_B, dim3(256), dim3(256), 0, stream, textW, 24, packT);
  hipLaunchKernelGGL(k_pack_B, dim3(256), dim3(256), 0, stream, faceW, 16, packF);
  hipLaunchKernelGGL(k_pack_B, dim3(128), dim3(256), 0, stream, audioW, 8, packA);

  hipLaunchKernelGGL(k_proj, dim3(128, 2), dim3(256), 0, stream, textF,  packT, textB,  tanhT, 768);
  hipLaunchKernelGGL(k_proj, dim3(128, 2), dim3(256), 0, stream, faceF,  packF, faceB,  tanhF, 512);
  hipLaunchKernelGGL(k_proj, dim3(128, 2), dim3(256), 0, stream, audioF, packA, audioB, tanhA, 256);

  hipLaunchKernelGGL(k_attdot, dim3(256), dim3(256), 0, stream,
                     tanhT, tanhF, tanhA, attW, utW, ufW, uaW, s6);
  hipLaunchKernelGGL(k_zerofeed, dim3(64), dim3(256), 0, stream, encfeed, ctr);
  hipLaunchKernelGGL(k_smax, dim3(96), dim3(256), 0, stream, s6, attn_tb, encfeed);

  // encoder: 3 LSTMs x 2 half-blocks
  hipLaunchKernelGGL(k_lstm, dim3(6), dim3(512), 0, stream,
                     packL, encfeed, decfeed, decH0, decC0,
                     enc_h, dec_h, exch, ctr, 0);
  hipLaunchKernelGGL(k_encout, dim3(256), dim3(256), 0, stream,
                     enc_h, encOutW, encOutB, enc_out_tb);
  hipLaunchKernelGGL(k_ctx, dim3(64), dim3(256), 0, stream,
                     attn_tb, enc_out_tb, target, decfeed);
  // decoder: 1 LSTM x 2 half-blocks
  hipLaunchKernelGGL(k_lstm, dim3(2), dim3(512), 0, stream,
                     packL, encfeed, decfeed, decH0, decC0,
                     enc_h, dec_h, exch, ctr, 3);
  hipLaunchKernelGGL(k_decout, dim3(256), dim3(256), 0, stream,
                     dec_h, out1W, out1B, out2W, out2B, out);
}

// Round 5
// 5520.503 us; speedup vs baseline: 4.8336x; 1.5811x over previous
//
#include <hip/hip_runtime.h>
#include <hip/hip_bf16.h>

typedef float f32x4 __attribute__((ext_vector_type(4)));
typedef __bf16 bf16x8 __attribute__((ext_vector_type(8)));
typedef unsigned long long ull;

#define DEVI static __device__ __forceinline__

DEVI unsigned f2bfu(float f){
  unsigned u = __builtin_bit_cast(unsigned, f);
  return (u + 0x7fffu + ((u >> 16) & 1u)) >> 16;   // RNE f32->bf16
}
DEVI float bf2f(unsigned s){
  return __builtin_bit_cast(float, s << 16);
}
DEVI float sigf(float x){ return 1.f/(1.f + __expf(-x)); }
DEVI float thf(float x){ return 2.f*sigf(2.f*x) - 1.f; }

// ---------------------------------------------------------------------------
// Pack LSTM weights (4 LSTMs) into A-fragment-linear bf16 layout.
// W_aug is (288 x 1024): rows 0..255 = Whh, rows 256..259 = Wih, row 260 = bias
// (consumed by a constant-1.0 input row), rest 0.
// frag (lstm, wglob(0..15), kt(0..8), g(0..3)); element (lane, j):
//   value = W_aug[32*kt + 8*(l>>4) + j][256*g + 16*wglob + (l&15)]
// ---------------------------------------------------------------------------
__global__ __launch_bounds__(256) void k_pack_lstm(
    const float* __restrict__ encWhh, const float* __restrict__ encWih,
    const float* __restrict__ decWhh, const float* __restrict__ decWih,
    const float* __restrict__ encB,   const float* __restrict__ decB,
    unsigned short* __restrict__ outp)
{
  const int total = 4*16*9*4*64*8;
  for (int e = blockIdx.x*blockDim.x + threadIdx.x; e < total; e += gridDim.x*blockDim.x){
    int j  = e & 7;
    int l  = (e >> 3) & 63;
    int g  = (e >> 9) & 3;
    int r  = e >> 11;          // (lstm*16 + w)*9 + kt
    int kt = r % 9;  r /= 9;
    int w  = r & 15;
    int lstm = r >> 4;
    int k = 32*kt + 8*(l >> 4) + j;
    int n = 256*g + 16*w + (l & 15);
    float v = 0.f;
    if (lstm < 3){
      if (k < 256)       v = encWhh[(lstm*256 + k)*1024 + n];
      else if (k < 259)  v = encWih[(lstm*3 + (k-256))*1024 + n];
      else if (k == 260) v = encB[lstm*1024 + n];
    } else {
      if (k < 256)       v = decWhh[k*1024 + n];
      else if (k < 260)  v = decWih[(k-256)*1024 + n];
      else if (k == 260) v = decB[n];
    }
    outp[e] = (unsigned short)f2bfu(v);
  }
}

// ---------------------------------------------------------------------------
// Pack projection weights (K x 256 f32) into B-fragment-linear bf16.
// ---------------------------------------------------------------------------
__global__ __launch_bounds__(256) void k_pack_B(
    const float* __restrict__ W, int KT, unsigned short* __restrict__ outp)
{
  const int total = 2*KT*8*64*8;
  for (int e = blockIdx.x*blockDim.x + threadIdx.x; e < total; e += gridDim.x*blockDim.x){
    int j  = e & 7;
    int l  = (e >> 3) & 63;
    int nt = (e >> 9) & 7;
    int r  = e >> 12;          // tn*KT + kt
    int kt = r % KT;
    int tn = r / KT;
    int k = 32*kt + 8*(l >> 4) + j;
    int n = 128*tn + 16*nt + (l & 15);
    outp[e] = (unsigned short)f2bfu(W[k*256 + n]);
  }
}

// ---------------------------------------------------------------------------
// Projection GEMM: C = A(16384xK) * B(Kx256) + bias, then tanh -> bf16 buffer.
// ---------------------------------------------------------------------------
__global__ __launch_bounds__(256) void k_proj(
    const float* __restrict__ A, const unsigned short* __restrict__ Bp,
    const float* __restrict__ bias, unsigned short* __restrict__ outT, int K)
{
  __shared__ unsigned char sA[8192];
  __shared__ unsigned char sB[8192];
  const int tid = threadIdx.x;
  const int l = tid & 63;
  const int wv = tid >> 6;
  const int wm = wv >> 1, wn = wv & 1;
  const int tm = blockIdx.x, tn = blockIdx.y;
  const int KT = K >> 5;

  f32x4 acc[4][4];
  #pragma unroll
  for (int a = 0; a < 4; ++a)
    #pragma unroll
    for (int cc = 0; cc < 4; ++cc)
      acc[a][cc] = f32x4{0.f,0.f,0.f,0.f};

  const int arow = tid >> 1;
  const float* Ap = A + (size_t)(tm*128 + arow)*K + (tid & 1)*16;
  const uint4* Bsrc = (const uint4*)Bp + (size_t)tn*KT*512 + tid*2;

  for (int kt = 0; kt < KT; ++kt){
    float4 f0 = *(const float4*)(Ap + kt*32);
    float4 f1 = *(const float4*)(Ap + kt*32 + 4);
    float4 f2 = *(const float4*)(Ap + kt*32 + 8);
    float4 f3 = *(const float4*)(Ap + kt*32 + 12);
    uint4 p0, p1;
    p0.x = f2bfu(f0.x) | (f2bfu(f0.y) << 16);
    p0.y = f2bfu(f0.z) | (f2bfu(f0.w) << 16);
    p0.z = f2bfu(f1.x) | (f2bfu(f1.y) << 16);
    p0.w = f2bfu(f1.z) | (f2bfu(f1.w) << 16);
    p1.x = f2bfu(f2.x) | (f2bfu(f2.y) << 16);
    p1.y = f2bfu(f2.z) | (f2bfu(f2.w) << 16);
    p1.z = f2bfu(f3.x) | (f2bfu(f3.y) << 16);
    p1.w = f2bfu(f3.z) | (f2bfu(f3.w) << 16);
    unsigned base = arow*64 + (tid & 1)*32;
    unsigned sw = (arow & 3) << 4;
    *(uint4*)(sA + ((base)      ^ sw)) = p0;
    *(uint4*)(sA + ((base + 16) ^ sw)) = p1;
    *((uint4*)sB + tid*2)     = Bsrc[kt*512];
    *((uint4*)sB + tid*2 + 1) = Bsrc[kt*512 + 1];
    __syncthreads();

    bf16x8 af[4], bf[4];
    #pragma unroll
    for (int a = 0; a < 4; ++a){
      unsigned row = 64*wm + 16*a + (l & 15);
      unsigned off = (row*64 + 16*(l >> 4)) ^ ((row & 3) << 4);
      af[a] = __builtin_bit_cast(bf16x8, *(const uint4*)(sA + off));
    }
    #pragma unroll
    for (int cc = 0; cc < 4; ++cc){
      unsigned off = ((4*wn + cc)*64 + l)*16;
      bf[cc] = __builtin_bit_cast(bf16x8, *(const uint4*)(sB + off));
    }
    #pragma unroll
    for (int a = 0; a < 4; ++a)
      #pragma unroll
      for (int cc = 0; cc < 4; ++cc)
        acc[a][cc] = __builtin_amdgcn_mfma_f32_16x16x32_bf16(af[a], bf[cc], acc[a][cc], 0, 0, 0);
    __syncthreads();
  }
  #pragma unroll
  for (int cc = 0; cc < 4; ++cc){
    int colg = tn*128 + 64*wn + 16*cc + (l & 15);
    float bs = bias[colg];
    #pragma unroll
    for (int a = 0; a < 4; ++a){
      int rowg = tm*128 + 64*wm + 16*a + 4*(l >> 4);
      #pragma unroll
      for (int r = 0; r < 4; ++r){
        outT[(size_t)(rowg + r)*256 + colg] = (unsigned short)f2bfu(thf(acc[a][cc][r] + bs));
      }
    }
  }
}

// ---------------------------------------------------------------------------
// Attention scalar dots. 7 partial dots -> 6 score fields (6,B,T) f32.
// ---------------------------------------------------------------------------
__global__ __launch_bounds__(256) void k_attdot(
    const unsigned short* __restrict__ tT, const unsigned short* __restrict__ tF,
    const unsigned short* __restrict__ tA,
    const float* __restrict__ attW, const float* __restrict__ utW,
    const float* __restrict__ ufW, const float* __restrict__ uaW,
    float* __restrict__ s6)
{
  const int l = threadIdx.x & 63;
  const int wid = (blockIdx.x*blockDim.x + threadIdx.x) >> 6;
  const int nw = (gridDim.x*blockDim.x) >> 6;
  float alo[4], ahi[4], wt[4], wf[4], wa[4];
  #pragma unroll
  for (int q = 0; q < 4; ++q){
    alo[q] = attW[4*l + q];
    ahi[q] = attW[256 + 4*l + q];
    wt[q]  = utW[4*l + q];
    wf[q]  = ufW[4*l + q];
    wa[q]  = uaW[4*l + q];
  }
  for (int r = wid; r < 16384; r += nw){
    uint2 vT = *(const uint2*)(tT + (size_t)r*256 + 4*l);
    uint2 vF = *(const uint2*)(tF + (size_t)r*256 + 4*l);
    uint2 vA = *(const uint2*)(tA + (size_t)r*256 + 4*l);
    float xt[4] = { bf2f(vT.x & 0xffff), bf2f(vT.x >> 16), bf2f(vT.y & 0xffff), bf2f(vT.y >> 16) };
    float xf[4] = { bf2f(vF.x & 0xffff), bf2f(vF.x >> 16), bf2f(vF.y & 0xffff), bf2f(vF.y >> 16) };
    float xa[4] = { bf2f(vA.x & 0xffff), bf2f(vA.x >> 16), bf2f(vA.y & 0xffff), bf2f(vA.y >> 16) };
    float ptlo = 0.f, ptu = 0.f, pflo = 0.f, pfhi = 0.f, pfu = 0.f, pahi = 0.f, pau = 0.f;
    #pragma unroll
    for (int q = 0; q < 4; ++q){
      ptlo += xt[q]*alo[q]; ptu += xt[q]*wt[q];
      pflo += xf[q]*alo[q]; pfhi += xf[q]*ahi[q]; pfu += xf[q]*wf[q];
      pahi += xa[q]*ahi[q]; pau += xa[q]*wa[q];
    }
    #pragma unroll
    for (int s = 1; s < 64; s <<= 1){
      ptlo += __shfl_xor(ptlo, s); ptu  += __shfl_xor(ptu, s);
      pflo += __shfl_xor(pflo, s); pfhi += __shfl_xor(pfhi, s);
      pfu  += __shfl_xor(pfu, s);  pahi += __shfl_xor(pahi, s);
      pau  += __shfl_xor(pau, s);
    }
    if (l == 0){
      int o = r;
      s6[o]             = ptlo + pfhi;
      s6[16384 + o]     = pflo + pahi;
      s6[2*16384 + o]   = ptlo + pahi;
      s6[3*16384 + o]   = ptu;
      s6[4*16384 + o]   = pfu;
      s6[5*16384 + o]   = pau;
    }
  }
}

// ---------------------------------------------------------------------------
__global__ __launch_bounds__(256) void k_zerofeed(unsigned short* __restrict__ encfeed,
                                                  int* __restrict__ tags)
{
  int i = blockIdx.x*blockDim.x + threadIdx.x;
  if (i < 16384) encfeed[i*4 + 3] = 0;
  if (i < 128) tags[i] = 0;
}

// ---------------------------------------------------------------------------
// Softmax over T per (field,b). Fields 0..2 -> attn_tb f32; 3..5 -> encfeed bf16.
// ---------------------------------------------------------------------------
__global__ __launch_bounds__(256) void k_smax(
    const float* __restrict__ s6, float* __restrict__ attn_tb,
    unsigned short* __restrict__ encfeed)
{
  __shared__ float red[4];
  const int f = blockIdx.x >> 4;
  const int b = blockIdx.x & 15;
  const int tid = threadIdx.x;
  const float* row = s6 + f*16384 + b*1024;
  float4 v = *(const float4*)(row + 4*tid);
  float mx = fmaxf(fmaxf(v.x, v.y), fmaxf(v.z, v.w));
  #pragma unroll
  for (int s = 1; s < 64; s <<= 1) mx = fmaxf(mx, __shfl_xor(mx, s));
  if ((tid & 63) == 0) red[tid >> 6] = mx;
  __syncthreads();
  mx = fmaxf(fmaxf(red[0], red[1]), fmaxf(red[2], red[3]));
  float e0 = __expf(v.x - mx), e1 = __expf(v.y - mx), e2 = __expf(v.z - mx), e3 = __expf(v.w - mx);
  float sm = e0 + e1 + e2 + e3;
  __syncthreads();
  #pragma unroll
  for (int s = 1; s < 64; s <<= 1) sm += __shfl_xor(sm, s);
  if ((tid & 63) == 0) red[tid >> 6] = sm;
  __syncthreads();
  sm = red[0] + red[1] + red[2] + red[3];
  float inv = 1.f/sm;
  float e[4] = {e0, e1, e2, e3};
  int ff = (f < 3) ? f : f - 3;
  #pragma unroll
  for (int q = 0; q < 4; ++q){
    int idx = ff*1024 + 4*tid + q;
    int tt = idx/3, kk = idx - 3*tt;
    if (f < 3) attn_tb[(tt*16 + b)*3 + kk] = e[q]*inv;
    else       encfeed[(tt*16 + b)*4 + kk] = (unsigned short)f2bfu(e[q]*inv);
  }
}

// ---------------------------------------------------------------------------
// Fused 4-LSTM pipelined recurrence. grid = 8 blocks x 512 threads.
// pair = blockIdx>>1 (0..2 = encoders, 3 = decoder), half = blockIdx&1.
// Each block owns h-cols [128*half,128*half+128); weights AGPR-resident.
// Pair halves exchange h(t+1) via LLC: relaxed data stores -> __syncthreads
// (drains vmcnt) -> single release tag store (value t+1) -> single-thread
// poll -> coalesced data load. Parity double-buffer on the data.
// Encoders additionally publish per-wave partial dots h(t).outW into a
// t-indexed array (never clobbered); the decoder polls enc tags (enc runs
// ~1 step ahead), sums partials into enc_out[t], keeps a 3-deep ring, and
// builds its own x-feed [target(t-1), ctx(t)] in-kernel.
// ---------------------------------------------------------------------------
__global__ __launch_bounds__(512, 2) void k_lstm(
    const unsigned short* __restrict__ packW,
    const unsigned short* __restrict__ encfeed,
    const float* __restrict__ target,
    const float* __restrict__ attn_tb,
    const float* __restrict__ encOutW,
    const float* __restrict__ encOutB,
    const float* __restrict__ dec_h0,
    const float* __restrict__ dec_c0,
    unsigned short* __restrict__ dec_h,
    ull* __restrict__ exch,       // [pair][parity][half][b][jg(32)] ull
    float* __restrict__ partials, // [t][pair(3)][half][wv(8)][b(16)] f32
    int* __restrict__ tags)       // [(pair*2+half)*16]
{
  __shared__ unsigned char hl[2][16*768];   // bf16 [b][k 0..287], row 768B, XOR swizzle
  __shared__ float ring[3][16][3];          // enc_out ring [slot][b][k] (dec only)
  const int tid = threadIdx.x;
  const int l = tid & 63;
  const int w = tid >> 6;                   // 0..7
  const int pair = blockIdx.x >> 1;         // 0..3
  const int half = blockIdx.x & 1;
  const int wglob = half*8 + w;             // 0..15
  const bool isdec = (pair == 3);

  const int b = l & 15;
  const int j0 = 16*wglob + 4*(l >> 4);
  const unsigned swb = (unsigned)(b & 7) << 4;

  float c[4];
  #pragma unroll
  for (int r = 0; r < 4; ++r) c[r] = isdec ? dec_c0[j0 + r] : 0.f;

  float wow[4] = {0.f, 0.f, 0.f, 0.f};
  if (!isdec){
    #pragma unroll
    for (int r = 0; r < 4; ++r) wow[r] = encOutW[pair*256 + j0 + r];
  }

  // full h(0) into buf0: 512 threads x 2 uint2 = 256 cols x 16 b
  {
    int ib = tid >> 5;
    int ic = (tid & 31) * 8;
    #pragma unroll
    for (int q = 0; q < 2; ++q){
      int c0 = ic + 4*q;
      uint2 hz;
      if (isdec){
        hz.x = f2bfu(dec_h0[c0])   | (f2bfu(dec_h0[c0+1]) << 16);
        hz.y = f2bfu(dec_h0[c0+2]) | (f2bfu(dec_h0[c0+3]) << 16);
      } else { hz.x = 0u; hz.y = 0u; }
      *(uint2*)(hl[0] + ((ib*768 + 2*c0) ^ ((unsigned)(ib & 7) << 4))) = hz;
    }
  }
  // rows 260..287 in both buffers: row 260 = 1.0 (bias row), rest 0
  if (tid < 224){
    int bufi = tid / 112;
    int r = tid % 112;
    int bb = r / 7, q = r % 7;
    uint2 z;
    z.x = (q == 0) ? 0x00003f80u : 0u;
    z.y = 0u;
    *(uint2*)(hl[bufi] + ((bb*768 + 520 + 8*q) ^ ((unsigned)(bb & 7) << 4))) = z;
  }
  // enc: x(0) rows 256..259 into buf0
  if (!isdec && tid < 16){
    uint2 gx0 = *(const uint2*)(encfeed + tid*4);
    *(uint2*)(hl[0] + ((tid*768 + 512) ^ ((unsigned)(tid & 7) << 4))) = gx0;
  }

  // preload 36 weight fragments into registers (pinned -> AGPR residency)
  const uint4* wb = (const uint4*)packW + ((size_t)(pair*16 + wglob)*36)*64 + l;
  uint4 wreg[36];
  #pragma unroll
  for (int i = 0; i < 36; ++i) wreg[i] = wb[i*64];
  #pragma unroll
  for (int i = 0; i < 36; ++i)
    asm volatile("" : "+v"(wreg[i].x), "+v"(wreg[i].y), "+v"(wreg[i].z), "+v"(wreg[i].w));

  int* mytag = tags + (pair*2 + half)*16;
  int* ptag  = tags + (pair*2 + (half^1))*16;

  // dec prologue: x(0) = [0, a0*eo[0]]
  if (isdec){
    if (tid == 0){
      #pragma unroll
      for (int k = 0; k < 3; ++k)
        #pragma unroll
        for (int h2 = 0; h2 < 2; ++h2)
          while (__hip_atomic_load(tags + (k*2 + h2)*16, __ATOMIC_ACQUIRE, __HIP_MEMORY_SCOPE_AGENT) < 1) {}
    }
    if (tid < 48){
      int bb = tid & 15, kk = tid >> 4;
      ring[1][bb][kk] = 0.f;
      ring[2][bb][kk] = 0.f;
    }
    __syncthreads();
    if (tid < 48){
      int bb = tid & 15, kk = tid >> 4;
      float s = encOutB[kk];
      #pragma unroll
      for (int h2 = 0; h2 < 2; ++h2)
        #pragma unroll
        for (int wv = 0; wv < 8; ++wv)
          s += __hip_atomic_load(partials + (((size_t)0*3 + kk)*2 + h2)*128 + wv*16 + bb,
                                 __ATOMIC_RELAXED, __HIP_MEMORY_SCOPE_AGENT);
      ring[0][bb][kk] = s;
    }
    __syncthreads();
    if (tid < 16){
      int bb = tid;
      float a0 = attn_tb[bb*3 + 0];
      unsigned o0 = 0u;   // shifted target at t=0 is the zero pad
      unsigned ok[3];
      #pragma unroll
      for (int k = 0; k < 3; ++k) ok[k] = f2bfu(a0 * ring[0][bb][k]);
      uint2 pk; pk.x = o0 | (ok[0] << 16); pk.y = ok[1] | (ok[2] << 16);
      *(uint2*)(hl[0] + ((bb*768 + 512) ^ ((unsigned)(bb & 7) << 4))) = pk;
    }
  }
  __syncthreads();

  for (int t = 0; t < 1024; ++t){
    const int p = t + 1;
    const unsigned char* cur = hl[t & 1];
    unsigned char* nxt = (unsigned char*)hl[p & 1];

    // B-frags: h_aug for this batch column
    bf16x8 af[9];
    #pragma unroll
    for (int kt = 0; kt < 9; ++kt){
      unsigned off = (unsigned)(b*768 + kt*64 + 16*(l >> 4)) ^ swb;
      af[kt] = __builtin_bit_cast(bf16x8, *(const uint4*)(cur + off));
    }

    // enc: prefetch x(t+1)
    uint2 gx;
    const bool ldx = (!isdec) && (t < 1023) && (tid < 16);
    if (ldx) gx = *(const uint2*)(encfeed + (size_t)p*64 + tid*4);

    f32x4 acc[4];
    #pragma unroll
    for (int g = 0; g < 4; ++g) acc[g] = f32x4{0.f,0.f,0.f,0.f};
    #pragma unroll
    for (int kt = 0; kt < 9; ++kt){
      #pragma unroll
      for (int g = 0; g < 4; ++g)
        acc[g] = __builtin_amdgcn_mfma_f32_16x16x32_bf16(
            __builtin_bit_cast(bf16x8, wreg[kt*4 + g]), af[kt], acc[g], 0, 0, 0);
    }

    // cell epilogue (bias via k=260 row)
    unsigned hp[4];
    #pragma unroll
    for (int r = 0; r < 4; ++r){
      float vi = sigf(acc[0][r]);
      float vf = sigf(acc[1][r]);
      float vg = thf (acc[2][r]);
      float vo = sigf(acc[3][r]);
      float cc = vf*c[r] + vi*vg;
      c[r] = cc;
      hp[r] = f2bfu(vo * thf(cc));
    }
    uint2 hpk; hpk.x = hp[0] | (hp[1] << 16); hpk.y = hp[2] | (hp[3] << 16);
    *(uint2*)(nxt + ((b*768 + 2*j0) ^ swb)) = hpk;

    if (isdec){
      *(uint2*)(dec_h + (size_t)(t*16 + b)*256 + j0) = hpk;
    } else {
      // partial dot h(t).outW for this wave, published per-wave
      float s = bf2f(hp[0])*wow[0] + bf2f(hp[1])*wow[1]
              + bf2f(hp[2])*wow[2] + bf2f(hp[3])*wow[3];
      s += __shfl_xor(s, 16);
      s += __shfl_xor(s, 32);
      if (l < 16)
        __hip_atomic_store(partials + (((size_t)t*3 + pair)*2 + half)*128 + w*16 + l,
                           s, __ATOMIC_RELAXED, __HIP_MEMORY_SCOPE_AGENT);
    }

    // publish own h half
    {
      ull val = ((ull)hpk.y << 32) | (ull)hpk.x;
      int jg = (j0 & 127) >> 2;
      __hip_atomic_store(exch + (((size_t)(pair*2 + (p & 1))*2 + half)*16 + b)*32 + jg,
                         val, __ATOMIC_RELAXED, __HIP_MEMORY_SCOPE_AGENT);
    }
    __syncthreads();   // drains all threads' stores (vmcnt 0 before barrier)
    if (tid == 0){
      __hip_atomic_store(mytag, p, __ATOMIC_RELEASE, __HIP_MEMORY_SCOPE_AGENT);
      while (__hip_atomic_load(ptag, __ATOMIC_ACQUIRE, __HIP_MEMORY_SCOPE_AGENT) < p) {}
      if (isdec && t < 1023){
        #pragma unroll
        for (int k = 0; k < 3; ++k)
          #pragma unroll
          for (int h2 = 0; h2 < 2; ++h2)
            while (__hip_atomic_load(tags + (k*2 + h2)*16, __ATOMIC_ACQUIRE, __HIP_MEMORY_SCOPE_AGENT) < p + 1) {}
      }
    }
    __syncthreads();

    // partner h half -> LDS
    {
      int pb = tid >> 5, pj = tid & 31;
      ull pv = __hip_atomic_load(exch + (((size_t)(pair*2 + (p & 1))*2 + (half^1))*16 + pb)*32 + pj,
                                 __ATOMIC_RELAXED, __HIP_MEMORY_SCOPE_AGENT);
      uint2 pk2; pk2.x = (unsigned)pv; pk2.y = (unsigned)(pv >> 32);
      *(uint2*)(nxt + ((pb*768 + 256*(half^1) + 8*pj) ^ ((unsigned)(pb & 7) << 4))) = pk2;
    }

    if (!isdec){
      if (ldx) *(uint2*)(nxt + ((tid*768 + 512) ^ ((unsigned)(tid & 7) << 4))) = gx;
    } else if (t < 1023){
      // eo[p] = sum of enc partials + bias; then x(p) = [target(p-1), ctx(p)]
      if (tid < 48){
        int bb = tid & 15, kk = tid >> 4;
        float s = encOutB[kk];
        #pragma unroll
        for (int h2 = 0; h2 < 2; ++h2)
          #pragma unroll
          for (int wv = 0; wv < 8; ++wv)
            s += __hip_atomic_load(partials + (((size_t)p*3 + kk)*2 + h2)*128 + wv*16 + bb,
                                   __ATOMIC_RELAXED, __HIP_MEMORY_SCOPE_AGENT);
        ring[p % 3][bb][kk] = s;
      }
      __syncthreads();
      if (tid < 16){
        int bb = tid;
        float a0 = attn_tb[((size_t)p*16 + bb)*3 + 0];
        float a1 = attn_tb[((size_t)p*16 + bb)*3 + 1];
        float a2 = attn_tb[((size_t)p*16 + bb)*3 + 2];
        int s0 = p % 3, s1 = (p + 2) % 3, s2 = (p + 1) % 3;
        unsigned o0 = f2bfu(target[bb*1024 + p - 1]);
        unsigned ok[3];
        #pragma unroll
        for (int k = 0; k < 3; ++k)
          ok[k] = f2bfu(a0*ring[s0][bb][k] + a1*ring[s1][bb][k] + a2*ring[s2][bb][k]);
        uint2 pk; pk.x = o0 | (ok[0] << 16); pk.y = ok[1] | (ok[2] << 16);
        *(uint2*)(nxt + ((bb*768 + 512) ^ ((unsigned)(bb & 7) << 4))) = pk;
      }
    }
    __syncthreads();
  }
}

// ---------------------------------------------------------------------------
// y[b,t] = relu(dec_h[t,b,:] @ W1 + b1) @ W2 + b2
// ---------------------------------------------------------------------------
__global__ __launch_bounds__(256) void k_decout(
    const unsigned short* __restrict__ dec_h, const float* __restrict__ W1,
    const float* __restrict__ b1, const float* __restrict__ W2,
    const float* __restrict__ b2, float* __restrict__ out)
{
  const int l = threadIdx.x & 63;
  const int wid = (blockIdx.x*blockDim.x + threadIdx.x) >> 6;
  const int nw = (gridDim.x*blockDim.x) >> 6;
  const int o = l >> 4, jc = l & 15;
  for (int e = wid; e < 16384; e += nw){
    int t = e >> 4, b = e & 15;
    const unsigned short* hr = dec_h + (size_t)(t*16 + b)*256 + jc*16;
    uint4 v0 = *(const uint4*)hr;
    uint4 v1 = *(const uint4*)(hr + 8);
    unsigned vv[8] = {v0.x, v0.y, v0.z, v0.w, v1.x, v1.y, v1.z, v1.w};
    float p = 0.f;
    #pragma unroll
    for (int q = 0; q < 8; ++q){
      int j = jc*16 + 2*q;
      p += bf2f(vv[q] & 0xffff) * W1[j*4 + o];
      p += bf2f(vv[q] >> 16)    * W1[(j + 1)*4 + o];
    }
    p += __shfl_xor(p, 1); p += __shfl_xor(p, 2);
    p += __shfl_xor(p, 4); p += __shfl_xor(p, 8);
    float v = 0.f;
    if (jc == 0) v = fmaxf(p + b1[o], 0.f) * W2[o];
    v += __shfl_xor(v, 16);
    v += __shfl_xor(v, 32);
    if (l == 0) out[b*1024 + t] = v + b2[0];
  }
}

// ---------------------------------------------------------------------------
extern "C" void kernel_launch(void* const* d_in, const int* in_sizes, int n_in,
                              void* d_out, int out_size, void* d_ws, size_t ws_size,
                              hipStream_t stream)
{
  const float* faceF   = (const float*)d_in[1];
  const float* audioF  = (const float*)d_in[2];
  const float* textF   = (const float*)d_in[3];
  const float* target  = (const float*)d_in[4];
  const float* textW   = (const float*)d_in[5];
  const float* textB   = (const float*)d_in[6];
  const float* faceW   = (const float*)d_in[7];
  const float* faceB   = (const float*)d_in[8];
  const float* audioW  = (const float*)d_in[9];
  const float* audioB  = (const float*)d_in[10];
  const float* attW    = (const float*)d_in[11];
  const float* utW     = (const float*)d_in[13];
  const float* ufW     = (const float*)d_in[15];
  const float* uaW     = (const float*)d_in[17];
  const float* encWih  = (const float*)d_in[19];
  const float* encWhh  = (const float*)d_in[20];
  const float* encB    = (const float*)d_in[21];
  const float* encOutW = (const float*)d_in[22];
  const float* encOutB = (const float*)d_in[23];
  const float* decWih  = (const float*)d_in[24];
  const float* decWhh  = (const float*)d_in[25];
  const float* decB    = (const float*)d_in[26];
  const float* decH0   = (const float*)d_in[27];
  const float* decC0   = (const float*)d_in[28];
  const float* out1W   = (const float*)d_in[29];
  const float* out1B   = (const float*)d_in[30];
  const float* out2W   = (const float*)d_in[31];
  const float* out2B   = (const float*)d_in[32];
  float* out = (float*)d_out;

  char* ws = (char*)d_ws;
  size_t off = 0;
  auto alloc = [&](size_t bytes) -> void* {
    void* p = ws + off;
    off += (bytes + 255) & ~(size_t)255;
    return p;
  };
  unsigned short* packL   = (unsigned short*)alloc(1179648ull*2);
  unsigned short* packT   = (unsigned short*)alloc(196608ull*2);
  unsigned short* packF   = (unsigned short*)alloc(131072ull*2);
  unsigned short* packA   = (unsigned short*)alloc(65536ull*2);
  unsigned short* tanhT   = (unsigned short*)alloc(16384ull*256*2);
  unsigned short* tanhF   = (unsigned short*)alloc(16384ull*256*2);
  unsigned short* tanhA   = (unsigned short*)alloc(16384ull*256*2);
  float*          s6      = (float*)alloc(6ull*16384*4);
  float*          attn_tb = (float*)alloc(49152ull*4);
  unsigned short* encfeed = (unsigned short*)alloc(65536ull*2);
  unsigned short* dec_h   = (unsigned short*)alloc(1024ull*16*256*2);
  ull*            exch    = (ull*)alloc(8192ull*8);
  float*          partials= (float*)alloc(1024ull*3*2*8*16*4);
  int*            tags    = (int*)alloc(512);
  if (off > ws_size) return;

  hipLaunchKernelGGL(k_pack_lstm, dim3(512), dim3(256), 0, stream,
                     encWhh, encWih, decWhh, decWih, encB, decB, packL);
  hipLaunchKernelGGL(k_pack_B, dim3(256), dim3(256), 0, stream, textW, 24, packT);
  hipLaunchKernelGGL(k_pack_B, dim3(256), dim3(256), 0, stream, faceW, 16, packF);
  hipLaunchKernelGGL(k_pack_B, dim3(128), dim3(256), 0, stream, audioW, 8, packA);

  hipLaunchKernelGGL(k_proj, dim3(128, 2), dim3(256), 0, stream, textF,  packT, textB,  tanhT, 768);
  hipLaunchKernelGGL(k_proj, dim3(128, 2), dim3(256), 0, stream, faceF,  packF, faceB,  tanhF, 512);
  hipLaunchKernelGGL(k_proj, dim3(128, 2), dim3(256), 0, stream, audioF, packA, audioB, tanhA, 256);

  hipLaunchKernelGGL(k_attdot, dim3(256), dim3(256), 0, stream,
                     tanhT, tanhF, tanhA, attW, utW, ufW, uaW, s6);
  hipLaunchKernelGGL(k_zerofeed, dim3(64), dim3(256), 0, stream, encfeed, tags);
  hipLaunchKernelGGL(k_smax, dim3(96), dim3(256), 0, stream, s6, attn_tb, encfeed);

  // fused pipelined 4-LSTM: 3 encoder pairs + 1 decoder pair = 8 blocks
  hipLaunchKernelGGL(k_lstm, dim3(8), dim3(512), 0, stream,
                     packL, encfeed, target, attn_tb, encOutW, encOutB,
                     decH0, decC0, dec_h, exch, partials, tags);
  hipLaunchKernelGGL(k_decout, dim3(256), dim3(256), 0, stream,
                     dec_h, out1W, out1B, out2W, out2B, out);
}

// Round 6
// 4852.037 us; speedup vs baseline: 5.4996x; 1.1378x over previous
//
#include <hip/hip_runtime.h>
#include <hip/hip_bf16.h>

typedef float f32x4 __attribute__((ext_vector_type(4)));
typedef __bf16 bf16x8 __attribute__((ext_vector_type(8)));
typedef unsigned long long ull;

#define DEVI static __device__ __forceinline__

DEVI unsigned f2bfu(float f){
  unsigned u = __builtin_bit_cast(unsigned, f);
  return (u + 0x7fffu + ((u >> 16) & 1u)) >> 16;   // RNE f32->bf16
}
DEVI float bf2f(unsigned s){
  return __builtin_bit_cast(float, s << 16);
}
DEVI float sigf(float x){ return 1.f/(1.f + __expf(-x)); }
DEVI float thf(float x){ return 2.f*sigf(2.f*x) - 1.f; }

DEVI ull allc(const ull* p){
  return __hip_atomic_load(p, __ATOMIC_RELAXED, __HIP_MEMORY_SCOPE_AGENT);
}
DEVI void alst(ull* p, ull v){
  __hip_atomic_store(p, v, __ATOMIC_RELAXED, __HIP_MEMORY_SCOPE_AGENT);
}

// ---------------------------------------------------------------------------
// Pack LSTM weights (4 LSTMs) into A-fragment-linear bf16 layout.
// W_aug is (288 x 1024): rows 0..255 = Whh, rows 256..259 = Wih, row 260 = bias
// (consumed by a constant-1.0 input row), rest 0.
// frag (lstm, wglob(0..15), kt(0..8), g(0..3)); element (lane, j):
//   value = W_aug[32*kt + 8*(l>>4) + j][256*g + 16*wglob + (l&15)]
// ---------------------------------------------------------------------------
__global__ __launch_bounds__(256) void k_pack_lstm(
    const float* __restrict__ encWhh, const float* __restrict__ encWih,
    const float* __restrict__ decWhh, const float* __restrict__ decWih,
    const float* __restrict__ encB,   const float* __restrict__ decB,
    unsigned short* __restrict__ outp)
{
  const int total = 4*16*9*4*64*8;
  for (int e = blockIdx.x*blockDim.x + threadIdx.x; e < total; e += gridDim.x*blockDim.x){
    int j  = e & 7;
    int l  = (e >> 3) & 63;
    int g  = (e >> 9) & 3;
    int r  = e >> 11;          // (lstm*16 + w)*9 + kt
    int kt = r % 9;  r /= 9;
    int w  = r & 15;
    int lstm = r >> 4;
    int k = 32*kt + 8*(l >> 4) + j;
    int n = 256*g + 16*w + (l & 15);
    float v = 0.f;
    if (lstm < 3){
      if (k < 256)       v = encWhh[(lstm*256 + k)*1024 + n];
      else if (k < 259)  v = encWih[(lstm*3 + (k-256))*1024 + n];
      else if (k == 260) v = encB[lstm*1024 + n];
    } else {
      if (k < 256)       v = decWhh[k*1024 + n];
      else if (k < 260)  v = decWih[(k-256)*1024 + n];
      else if (k == 260) v = decB[n];
    }
    outp[e] = (unsigned short)f2bfu(v);
  }
}

// ---------------------------------------------------------------------------
// Pack projection weights (K x 256 f32) into B-fragment-linear bf16.
// ---------------------------------------------------------------------------
__global__ __launch_bounds__(256) void k_pack_B(
    const float* __restrict__ W, int KT, unsigned short* __restrict__ outp)
{
  const int total = 2*KT*8*64*8;
  for (int e = blockIdx.x*blockDim.x + threadIdx.x; e < total; e += gridDim.x*blockDim.x){
    int j  = e & 7;
    int l  = (e >> 3) & 63;
    int nt = (e >> 9) & 7;
    int r  = e >> 12;          // tn*KT + kt
    int kt = r % KT;
    int tn = r / KT;
    int k = 32*kt + 8*(l >> 4) + j;
    int n = 128*tn + 16*nt + (l & 15);
    outp[e] = (unsigned short)f2bfu(W[k*256 + n]);
  }
}

// ---------------------------------------------------------------------------
// Projection GEMM: C = A(16384xK) * B(Kx256) + bias, then tanh -> bf16 buffer.
// ---------------------------------------------------------------------------
__global__ __launch_bounds__(256) void k_proj(
    const float* __restrict__ A, const unsigned short* __restrict__ Bp,
    const float* __restrict__ bias, unsigned short* __restrict__ outT, int K)
{
  __shared__ unsigned char sA[8192];
  __shared__ unsigned char sB[8192];
  const int tid = threadIdx.x;
  const int l = tid & 63;
  const int wv = tid >> 6;
  const int wm = wv >> 1, wn = wv & 1;
  const int tm = blockIdx.x, tn = blockIdx.y;
  const int KT = K >> 5;

  f32x4 acc[4][4];
  #pragma unroll
  for (int a = 0; a < 4; ++a)
    #pragma unroll
    for (int cc = 0; cc < 4; ++cc)
      acc[a][cc] = f32x4{0.f,0.f,0.f,0.f};

  const int arow = tid >> 1;
  const float* Ap = A + (size_t)(tm*128 + arow)*K + (tid & 1)*16;
  const uint4* Bsrc = (const uint4*)Bp + (size_t)tn*KT*512 + tid*2;

  for (int kt = 0; kt < KT; ++kt){
    float4 f0 = *(const float4*)(Ap + kt*32);
    float4 f1 = *(const float4*)(Ap + kt*32 + 4);
    float4 f2 = *(const float4*)(Ap + kt*32 + 8);
    float4 f3 = *(const float4*)(Ap + kt*32 + 12);
    uint4 p0, p1;
    p0.x = f2bfu(f0.x) | (f2bfu(f0.y) << 16);
    p0.y = f2bfu(f0.z) | (f2bfu(f0.w) << 16);
    p0.z = f2bfu(f1.x) | (f2bfu(f1.y) << 16);
    p0.w = f2bfu(f1.z) | (f2bfu(f1.w) << 16);
    p1.x = f2bfu(f2.x) | (f2bfu(f2.y) << 16);
    p1.y = f2bfu(f2.z) | (f2bfu(f2.w) << 16);
    p1.z = f2bfu(f3.x) | (f2bfu(f3.y) << 16);
    p1.w = f2bfu(f3.z) | (f2bfu(f3.w) << 16);
    unsigned base = arow*64 + (tid & 1)*32;
    unsigned sw = (arow & 3) << 4;
    *(uint4*)(sA + ((base)      ^ sw)) = p0;
    *(uint4*)(sA + ((base + 16) ^ sw)) = p1;
    *((uint4*)sB + tid*2)     = Bsrc[kt*512];
    *((uint4*)sB + tid*2 + 1) = Bsrc[kt*512 + 1];
    __syncthreads();

    bf16x8 af[4], bf[4];
    #pragma unroll
    for (int a = 0; a < 4; ++a){
      unsigned row = 64*wm + 16*a + (l & 15);
      unsigned off = (row*64 + 16*(l >> 4)) ^ ((row & 3) << 4);
      af[a] = __builtin_bit_cast(bf16x8, *(const uint4*)(sA + off));
    }
    #pragma unroll
    for (int cc = 0; cc < 4; ++cc){
      unsigned off = ((4*wn + cc)*64 + l)*16;
      bf[cc] = __builtin_bit_cast(bf16x8, *(const uint4*)(sB + off));
    }
    #pragma unroll
    for (int a = 0; a < 4; ++a)
      #pragma unroll
      for (int cc = 0; cc < 4; ++cc)
        acc[a][cc] = __builtin_amdgcn_mfma_f32_16x16x32_bf16(af[a], bf[cc], acc[a][cc], 0, 0, 0);
    __syncthreads();
  }
  #pragma unroll
  for (int cc = 0; cc < 4; ++cc){
    int colg = tn*128 + 64*wn + 16*cc + (l & 15);
    float bs = bias[colg];
    #pragma unroll
    for (int a = 0; a < 4; ++a){
      int rowg = tm*128 + 64*wm + 16*a + 4*(l >> 4);
      #pragma unroll
      for (int r = 0; r < 4; ++r){
        outT[(size_t)(rowg + r)*256 + colg] = (unsigned short)f2bfu(thf(acc[a][cc][r] + bs));
      }
    }
  }
}

// ---------------------------------------------------------------------------
// Attention scalar dots. 7 partial dots -> 6 score fields (6,B,T) f32.
// ---------------------------------------------------------------------------
__global__ __launch_bounds__(256) void k_attdot(
    const unsigned short* __restrict__ tT, const unsigned short* __restrict__ tF,
    const unsigned short* __restrict__ tA,
    const float* __restrict__ attW, const float* __restrict__ utW,
    const float* __restrict__ ufW, const float* __restrict__ uaW,
    float* __restrict__ s6)
{
  const int l = threadIdx.x & 63;
  const int wid = (blockIdx.x*blockDim.x + threadIdx.x) >> 6;
  const int nw = (gridDim.x*blockDim.x) >> 6;
  float alo[4], ahi[4], wt[4], wf[4], wa[4];
  #pragma unroll
  for (int q = 0; q < 4; ++q){
    alo[q] = attW[4*l + q];
    ahi[q] = attW[256 + 4*l + q];
    wt[q]  = utW[4*l + q];
    wf[q]  = ufW[4*l + q];
    wa[q]  = uaW[4*l + q];
  }
  for (int r = wid; r < 16384; r += nw){
    uint2 vT = *(const uint2*)(tT + (size_t)r*256 + 4*l);
    uint2 vF = *(const uint2*)(tF + (size_t)r*256 + 4*l);
    uint2 vA = *(const uint2*)(tA + (size_t)r*256 + 4*l);
    float xt[4] = { bf2f(vT.x & 0xffff), bf2f(vT.x >> 16), bf2f(vT.y & 0xffff), bf2f(vT.y >> 16) };
    float xf[4] = { bf2f(vF.x & 0xffff), bf2f(vF.x >> 16), bf2f(vF.y & 0xffff), bf2f(vF.y >> 16) };
    float xa[4] = { bf2f(vA.x & 0xffff), bf2f(vA.x >> 16), bf2f(vA.y & 0xffff), bf2f(vA.y >> 16) };
    float ptlo = 0.f, ptu = 0.f, pflo = 0.f, pfhi = 0.f, pfu = 0.f, pahi = 0.f, pau = 0.f;
    #pragma unroll
    for (int q = 0; q < 4; ++q){
      ptlo += xt[q]*alo[q]; ptu += xt[q]*wt[q];
      pflo += xf[q]*alo[q]; pfhi += xf[q]*ahi[q]; pfu += xf[q]*wf[q];
      pahi += xa[q]*ahi[q]; pau += xa[q]*wa[q];
    }
    #pragma unroll
    for (int s = 1; s < 64; s <<= 1){
      ptlo += __shfl_xor(ptlo, s); ptu  += __shfl_xor(ptu, s);
      pflo += __shfl_xor(pflo, s); pfhi += __shfl_xor(pfhi, s);
      pfu  += __shfl_xor(pfu, s);  pahi += __shfl_xor(pahi, s);
      pau  += __shfl_xor(pau, s);
    }
    if (l == 0){
      int o = r;
      s6[o]             = ptlo + pfhi;
      s6[16384 + o]     = pflo + pahi;
      s6[2*16384 + o]   = ptlo + pahi;
      s6[3*16384 + o]   = ptu;
      s6[4*16384 + o]   = pfu;
      s6[5*16384 + o]   = pau;
    }
  }
}

// ---------------------------------------------------------------------------
__global__ __launch_bounds__(256) void k_zerofeed(unsigned short* __restrict__ encfeed)
{
  int i = blockIdx.x*blockDim.x + threadIdx.x;
  if (i < 16384) encfeed[i*4 + 3] = 0;
}

// Zero the exch+partials tag region every launch (replay-safe tags).
__global__ __launch_bounds__(256) void k_zerows(uint4* __restrict__ p, int n)
{
  for (int i = blockIdx.x*blockDim.x + threadIdx.x; i < n; i += gridDim.x*blockDim.x)
    p[i] = uint4{0u,0u,0u,0u};
}

// ---------------------------------------------------------------------------
// Softmax over T per (field,b). Fields 0..2 -> attn_tb f32; 3..5 -> encfeed bf16.
// ---------------------------------------------------------------------------
__global__ __launch_bounds__(256) void k_smax(
    const float* __restrict__ s6, float* __restrict__ attn_tb,
    unsigned short* __restrict__ encfeed)
{
  __shared__ float red[4];
  const int f = blockIdx.x >> 4;
  const int b = blockIdx.x & 15;
  const int tid = threadIdx.x;
  const float* row = s6 + f*16384 + b*1024;
  float4 v = *(const float4*)(row + 4*tid);
  float mx = fmaxf(fmaxf(v.x, v.y), fmaxf(v.z, v.w));
  #pragma unroll
  for (int s = 1; s < 64; s <<= 1) mx = fmaxf(mx, __shfl_xor(mx, s));
  if ((tid & 63) == 0) red[tid >> 6] = mx;
  __syncthreads();
  mx = fmaxf(fmaxf(red[0], red[1]), fmaxf(red[2], red[3]));
  float e0 = __expf(v.x - mx), e1 = __expf(v.y - mx), e2 = __expf(v.z - mx), e3 = __expf(v.w - mx);
  float sm = e0 + e1 + e2 + e3;
  __syncthreads();
  #pragma unroll
  for (int s = 1; s < 64; s <<= 1) sm += __shfl_xor(sm, s);
  if ((tid & 63) == 0) red[tid >> 6] = sm;
  __syncthreads();
  sm = red[0] + red[1] + red[2] + red[3];
  float inv = 1.f/sm;
  float e[4] = {e0, e1, e2, e3};
  int ff = (f < 3) ? f : f - 3;
  #pragma unroll
  for (int q = 0; q < 4; ++q){
    int idx = ff*1024 + 4*tid + q;
    int tt = idx/3, kk = idx - 3*tt;
    if (f < 3) attn_tb[(tt*16 + b)*3 + kk] = e[q]*inv;
    else       encfeed[(tt*16 + b)*4 + kk] = (unsigned short)f2bfu(e[q]*inv);
  }
}

// ---------------------------------------------------------------------------
// Fused 4-LSTM pipelined recurrence. grid = 8 blocks x 512 threads.
// pair = blockIdx>>1 (0..2 = encoders, 3 = decoder), half = blockIdx&1.
// Weights AGPR-resident ("+a" pins; MFMA reads srcA from AGPR on gfx950).
// h exchange: 64-bit words (step-tag<<32 | 2xbf16), parity double-buffered,
// relaxed agent atomics, batched two-phase polls -> ONE LLC round trip.
// Enc partials: tag-embedded t-indexed words; dec polls them directly
// (96 threads x 8-word batches) concurrently with its h-poll.
// Enc: 1 barrier/step. Dec: 2 barriers/step.
// ---------------------------------------------------------------------------
__global__ __launch_bounds__(512, 2) void k_lstm(
    const unsigned short* __restrict__ packW,
    const unsigned short* __restrict__ encfeed,
    const float* __restrict__ target,
    const float* __restrict__ attn_tb,
    const float* __restrict__ encOutW,
    const float* __restrict__ encOutB,
    const float* __restrict__ dec_h0,
    const float* __restrict__ dec_c0,
    unsigned short* __restrict__ dec_h,
    ull* __restrict__ exch,       // [pair][parity][half][b][word64] tag|2bf16
    ull* __restrict__ partials)   // [t][pair3][half][wv8][b16] tag(t+1)|f32
{
  __shared__ unsigned char hl[2][16*768];   // bf16 [b][k 0..287], row 768B, XOR swizzle
  __shared__ float ring[3][16][3];          // enc_out ring [slot][b][k] (dec only)
  __shared__ float eo_part[2][48];          // per-half partial sums (dec only)
  const int tid = threadIdx.x;
  const int l = tid & 63;
  const int w = tid >> 6;                   // 0..7
  const int pair = blockIdx.x >> 1;         // 0..3
  const int half = blockIdx.x & 1;
  const int wglob = half*8 + w;             // 0..15
  const bool isdec = (pair == 3);

  const int b = l & 15;
  const int j0 = 16*wglob + 4*(l >> 4);
  const unsigned swb = (unsigned)(b & 7) << 4;

  float c[4];
  #pragma unroll
  for (int r = 0; r < 4; ++r) c[r] = isdec ? dec_c0[j0 + r] : 0.f;

  float wow[4] = {0.f, 0.f, 0.f, 0.f};
  if (!isdec){
    #pragma unroll
    for (int r = 0; r < 4; ++r) wow[r] = encOutW[pair*256 + j0 + r];
  }
  float eb[3] = {0.f, 0.f, 0.f};
  if (isdec && tid < 16){
    #pragma unroll
    for (int k = 0; k < 3; ++k) eb[k] = encOutB[k];
  }

  // full h(0) into buf0: 512 threads x 2 uint2 = 256 cols x 16 b
  {
    int ib = tid >> 5;
    int ic = (tid & 31) * 8;
    #pragma unroll
    for (int q = 0; q < 2; ++q){
      int c0 = ic + 4*q;
      uint2 hz;
      if (isdec){
        hz.x = f2bfu(dec_h0[c0])   | (f2bfu(dec_h0[c0+1]) << 16);
        hz.y = f2bfu(dec_h0[c0+2]) | (f2bfu(dec_h0[c0+3]) << 16);
      } else { hz.x = 0u; hz.y = 0u; }
      *(uint2*)(hl[0] + ((ib*768 + 2*c0) ^ ((unsigned)(ib & 7) << 4))) = hz;
    }
  }
  // rows 260..287 in both buffers: row 260 = 1.0 (bias row), rest 0
  if (tid < 224){
    int bufi = tid / 112;
    int r = tid % 112;
    int bb = r / 7, q = r % 7;
    uint2 z;
    z.x = (q == 0) ? 0x00003f80u : 0u;
    z.y = 0u;
    *(uint2*)(hl[bufi] + ((bb*768 + 520 + 8*q) ^ ((unsigned)(bb & 7) << 4))) = z;
  }
  // enc: x(0) rows 256..259 into buf0
  if (!isdec && tid < 16){
    uint2 gx0 = *(const uint2*)(encfeed + tid*4);
    *(uint2*)(hl[0] + ((tid*768 + 512) ^ ((unsigned)(tid & 7) << 4))) = gx0;
  }

  // preload 36 weight fragments, pin into AGPRs (MFMA srcA reads AGPR on gfx950)
  const uint4* wb = (const uint4*)packW + ((size_t)(pair*16 + wglob)*36)*64 + l;
  uint4 wreg[36];
  #pragma unroll
  for (int i = 0; i < 36; ++i) wreg[i] = wb[i*64];
  #pragma unroll
  for (int i = 0; i < 36; ++i){
    unsigned t0 = wreg[i].x, t1 = wreg[i].y, t2 = wreg[i].z, t3 = wreg[i].w;
    asm volatile("" : "+a"(t0), "+a"(t1), "+a"(t2), "+a"(t3));
    wreg[i].x = t0; wreg[i].y = t1; wreg[i].z = t2; wreg[i].w = t3;
  }

  // dec prologue: eo(0) from enc partials[0] (tag==1), x(0) = [0, a0*eo(0)]
  if (isdec){
    if (tid < 96){
      int bb = tid & 15, kk = (tid >> 4) % 3, h2 = tid / 48;
      const ull* p8 = partials + (((size_t)0*3 + kk)*2 + h2)*128 + bb;
      ull v[8];
      #pragma unroll
      for (int wv = 0; wv < 8; ++wv) v[wv] = allc(p8 + wv*16);
      bool ok = false;
      while (!ok){
        ok = true;
        #pragma unroll
        for (int wv = 0; wv < 8; ++wv)
          if ((unsigned)(v[wv] >> 32) != 1u){ v[wv] = allc(p8 + wv*16); ok = false; }
      }
      float s = 0.f;
      #pragma unroll
      for (int wv = 0; wv < 8; ++wv) s += __builtin_bit_cast(float, (unsigned)v[wv]);
      eo_part[h2][kk*16 + bb] = s;
    }
    __syncthreads();
    if (tid < 16){
      int bb = tid;
      float a0 = attn_tb[bb*3 + 0];
      unsigned ok3[3];
      #pragma unroll
      for (int k = 0; k < 3; ++k){
        float eo = eb[k] + eo_part[0][k*16 + bb] + eo_part[1][k*16 + bb];
        ring[0][bb][k] = eo; ring[1][bb][k] = 0.f; ring[2][bb][k] = 0.f;
        ok3[k] = f2bfu(a0*eo);
      }
      uint2 pk; pk.x = (ok3[0] << 16); pk.y = ok3[1] | (ok3[2] << 16);
      *(uint2*)(hl[0] + ((bb*768 + 512) ^ ((unsigned)(bb & 7) << 4))) = pk;
    }
  }
  __syncthreads();

  for (int t = 0; t < 1024; ++t){
    const int p = t + 1;
    const unsigned char* cur = hl[t & 1];
    unsigned char* nxt = (unsigned char*)hl[p & 1];

    // B-frags: h_aug for this batch column
    bf16x8 af[9];
    #pragma unroll
    for (int kt = 0; kt < 9; ++kt){
      unsigned off = (unsigned)(b*768 + kt*64 + 16*(l >> 4)) ^ swb;
      af[kt] = __builtin_bit_cast(bf16x8, *(const uint4*)(cur + off));
    }

    // enc: prefetch x(t+1); dec builders: prefetch attn(p), target(t)
    uint2 gx;
    const bool ldx = (!isdec) && (t < 1023) && (tid < 16);
    if (ldx) gx = *(const uint2*)(encfeed + (size_t)p*64 + tid*4);
    float at0 = 0.f, at1 = 0.f, at2 = 0.f, tg = 0.f;
    const bool bld = isdec && (t < 1023) && (tid < 16);
    if (bld){
      at0 = attn_tb[((size_t)p*16 + tid)*3 + 0];
      at1 = attn_tb[((size_t)p*16 + tid)*3 + 1];
      at2 = attn_tb[((size_t)p*16 + tid)*3 + 2];
      tg  = target[tid*1024 + t];
    }

    f32x4 acc[4];
    #pragma unroll
    for (int g = 0; g < 4; ++g) acc[g] = f32x4{0.f,0.f,0.f,0.f};
    #pragma unroll
    for (int kt = 0; kt < 9; ++kt){
      #pragma unroll
      for (int g = 0; g < 4; ++g)
        acc[g] = __builtin_amdgcn_mfma_f32_16x16x32_bf16(
            __builtin_bit_cast(bf16x8, wreg[kt*4 + g]), af[kt], acc[g], 0, 0, 0);
    }

    // cell epilogue (bias via k=260 row)
    unsigned hp[4];
    #pragma unroll
    for (int r = 0; r < 4; ++r){
      float vi = sigf(acc[0][r]);
      float vf = sigf(acc[1][r]);
      float vg = thf (acc[2][r]);
      float vo = sigf(acc[3][r]);
      float cc = vf*c[r] + vi*vg;
      c[r] = cc;
      hp[r] = f2bfu(vo * thf(cc));
    }
    uint2 hpk; hpk.x = hp[0] | (hp[1] << 16); hpk.y = hp[2] | (hp[3] << 16);
    *(uint2*)(nxt + ((b*768 + 2*j0) ^ swb)) = hpk;

    if (isdec){
      *(uint2*)(dec_h + (size_t)(t*16 + b)*256 + j0) = hpk;
    } else {
      // per-wave partial dot h(t).outW, published with embedded tag t+1
      float s = bf2f(hp[0])*wow[0] + bf2f(hp[1])*wow[1]
              + bf2f(hp[2])*wow[2] + bf2f(hp[3])*wow[3];
      s += __shfl_xor(s, 16);
      s += __shfl_xor(s, 32);
      if (l < 16)
        alst(partials + (((size_t)t*3 + pair)*2 + half)*128 + w*16 + l,
             ((ull)(unsigned)p << 32) | (ull)__builtin_bit_cast(unsigned, s));
    }

    if (t < 1023){
      // publish own h half: 2 tag-embedded words
      {
        size_t xs = ((((size_t)pair*2 + (p & 1))*2 + half)*16 + b)*64
                  + ((unsigned)(j0 & 127) >> 1);
        alst(exch + xs,     ((ull)(unsigned)p << 32) | (ull)hpk.x);
        alst(exch + xs + 1, ((ull)(unsigned)p << 32) | (ull)hpk.y);
      }
      // poll partner h (all threads, 2 words) + dec partials (96 threads, 8 words)
      const int pb2 = tid >> 5, pj = tid & 31;
      const ull* rb = exch + ((((size_t)pair*2 + (p & 1))*2 + (half^1))*16 + pb2)*64 + pj*2;
      ull v0 = allc(rb), v1 = allc(rb + 1);
      const bool pol = isdec && (tid < 96);
      const int kk = (tid >> 4) % 3, h2 = tid / 48, bb = tid & 15;
      const ull* p8 = partials + (((size_t)p*3 + kk)*2 + h2)*128 + bb;
      ull pv[8];
      if (pol){
        #pragma unroll
        for (int wv = 0; wv < 8; ++wv) pv[wv] = allc(p8 + wv*16);
      }
      while (((unsigned)(v0 >> 32) != (unsigned)p) || ((unsigned)(v1 >> 32) != (unsigned)p)){
        if ((unsigned)(v0 >> 32) != (unsigned)p) v0 = allc(rb);
        if ((unsigned)(v1 >> 32) != (unsigned)p) v1 = allc(rb + 1);
      }
      uint2 pk2; pk2.x = (unsigned)v0; pk2.y = (unsigned)v1;
      *(uint2*)(nxt + ((pb2*768 + 256*(half^1) + 8*pj) ^ ((unsigned)(pb2 & 7) << 4))) = pk2;
      if (pol){
        const unsigned want = (unsigned)(p + 1);
        bool ok = false;
        while (!ok){
          ok = true;
          #pragma unroll
          for (int wv = 0; wv < 8; ++wv)
            if ((unsigned)(pv[wv] >> 32) != want){ pv[wv] = allc(p8 + wv*16); ok = false; }
        }
        float s2 = 0.f;
        #pragma unroll
        for (int wv = 0; wv < 8; ++wv) s2 += __builtin_bit_cast(float, (unsigned)pv[wv]);
        eo_part[h2][kk*16 + bb] = s2;
      }
      if (ldx) *(uint2*)(nxt + ((tid*768 + 512) ^ ((unsigned)(tid & 7) << 4))) = gx;
      __syncthreads();
      if (isdec){
        if (tid < 16){
          int s0 = p % 3, s1 = (p + 2) % 3, s2i = (p + 1) % 3;
          unsigned ok3[3];
          #pragma unroll
          for (int k = 0; k < 3; ++k){
            float eo = eb[k] + eo_part[0][k*16 + tid] + eo_part[1][k*16 + tid];
            ring[s0][tid][k] = eo;
            ok3[k] = f2bfu(at0*eo + at1*ring[s1][tid][k] + at2*ring[s2i][tid][k]);
          }
          uint2 pk3; pk3.x = f2bfu(tg) | (ok3[0] << 16); pk3.y = ok3[1] | (ok3[2] << 16);
          *(uint2*)(nxt + ((tid*768 + 512) ^ ((unsigned)(tid & 7) << 4))) = pk3;
        }
        __syncthreads();
      }
    }
  }
}

// ---------------------------------------------------------------------------
// y[b,t] = relu(dec_h[t,b,:] @ W1 + b1) @ W2 + b2
// ---------------------------------------------------------------------------
__global__ __launch_bounds__(256) void k_decout(
    const unsigned short* __restrict__ dec_h, const float* __restrict__ W1,
    const float* __restrict__ b1, const float* __restrict__ W2,
    const float* __restrict__ b2, float* __restrict__ out)
{
  const int l = threadIdx.x & 63;
  const int wid = (blockIdx.x*blockDim.x + threadIdx.x) >> 6;
  const int nw = (gridDim.x*blockDim.x) >> 6;
  const int o = l >> 4, jc = l & 15;
  for (int e = wid; e < 16384; e += nw){
    int t = e >> 4, b = e & 15;
    const unsigned short* hr = dec_h + (size_t)(t*16 + b)*256 + jc*16;
    uint4 v0 = *(const uint4*)hr;
    uint4 v1 = *(const uint4*)(hr + 8);
    unsigned vv[8] = {v0.x, v0.y, v0.z, v0.w, v1.x, v1.y, v1.z, v1.w};
    float p = 0.f;
    #pragma unroll
    for (int q = 0; q < 8; ++q){
      int j = jc*16 + 2*q;
      p += bf2f(vv[q] & 0xffff) * W1[j*4 + o];
      p += bf2f(vv[q] >> 16)    * W1[(j + 1)*4 + o];
    }
    p += __shfl_xor(p, 1); p += __shfl_xor(p, 2);
    p += __shfl_xor(p, 4); p += __shfl_xor(p, 8);
    float v = 0.f;
    if (jc == 0) v = fmaxf(p + b1[o], 0.f) * W2[o];
    v += __shfl_xor(v, 16);
    v += __shfl_xor(v, 32);
    if (l == 0) out[b*1024 + t] = v + b2[0];
  }
}

// ---------------------------------------------------------------------------
extern "C" void kernel_launch(void* const* d_in, const int* in_sizes, int n_in,
                              void* d_out, int out_size, void* d_ws, size_t ws_size,
                              hipStream_t stream)
{
  const float* faceF   = (const float*)d_in[1];
  const float* audioF  = (const float*)d_in[2];
  const float* textF   = (const float*)d_in[3];
  const float* target  = (const float*)d_in[4];
  const float* textW   = (const float*)d_in[5];
  const float* textB   = (const float*)d_in[6];
  const float* faceW   = (const float*)d_in[7];
  const float* faceB   = (const float*)d_in[8];
  const float* audioW  = (const float*)d_in[9];
  const float* audioB  = (const float*)d_in[10];
  const float* attW    = (const float*)d_in[11];
  const float* utW     = (const float*)d_in[13];
  const float* ufW     = (const float*)d_in[15];
  const float* uaW     = (const float*)d_in[17];
  const float* encWih  = (const float*)d_in[19];
  const float* encWhh  = (const float*)d_in[20];
  const float* encB    = (const float*)d_in[21];
  const float* encOutW = (const float*)d_in[22];
  const float* encOutB = (const float*)d_in[23];
  const float* decWih  = (const float*)d_in[24];
  const float* decWhh  = (const float*)d_in[25];
  const float* decB    = (const float*)d_in[26];
  const float* decH0   = (const float*)d_in[27];
  const float* decC0   = (const float*)d_in[28];
  const float* out1W   = (const float*)d_in[29];
  const float* out1B   = (const float*)d_in[30];
  const float* out2W   = (const float*)d_in[31];
  const float* out2B   = (const float*)d_in[32];
  float* out = (float*)d_out;

  char* ws = (char*)d_ws;
  size_t off = 0;
  auto alloc = [&](size_t bytes) -> void* {
    void* p = ws + off;
    off += (bytes + 255) & ~(size_t)255;
    return p;
  };
  unsigned short* packL   = (unsigned short*)alloc(1179648ull*2);
  unsigned short* packT   = (unsigned short*)alloc(196608ull*2);
  unsigned short* packF   = (unsigned short*)alloc(131072ull*2);
  unsigned short* packA   = (unsigned short*)alloc(65536ull*2);
  unsigned short* tanhT   = (unsigned short*)alloc(16384ull*256*2);
  unsigned short* tanhF   = (unsigned short*)alloc(16384ull*256*2);
  unsigned short* tanhA   = (unsigned short*)alloc(16384ull*256*2);
  float*          s6      = (float*)alloc(6ull*16384*4);
  float*          attn_tb = (float*)alloc(49152ull*4);
  unsigned short* encfeed = (unsigned short*)alloc(65536ull*2);
  unsigned short* dec_h   = (unsigned short*)alloc(1024ull*16*256*2);
  ull*            exch    = (ull*)alloc(16384ull*8);        // 128 KB
  ull*            partials= (ull*)alloc(786432ull*8);       // 6 MB (contiguous after exch)
  if (off > ws_size) return;

  hipLaunchKernelGGL(k_pack_lstm, dim3(512), dim3(256), 0, stream,
                     encWhh, encWih, decWhh, decWih, encB, decB, packL);
  hipLaunchKernelGGL(k_pack_B, dim3(256), dim3(256), 0, stream, textW, 24, packT);
  hipLaunchKernelGGL(k_pack_B, dim3(256), dim3(256), 0, stream, faceW, 16, packF);
  hipLaunchKernelGGL(k_pack_B, dim3(128), dim3(256), 0, stream, audioW, 8, packA);
  // zero tag regions (exch + partials are contiguous allocations)
  hipLaunchKernelGGL(k_zerows, dim3(1024), dim3(256), 0, stream,
                     (uint4*)exch, (int)((16384ull*8 + 786432ull*8) / 16));

  hipLaunchKernelGGL(k_proj, dim3(128, 2), dim3(256), 0, stream, textF,  packT, textB,  tanhT, 768);
  hipLaunchKernelGGL(k_proj, dim3(128, 2), dim3(256), 0, stream, faceF,  packF, faceB,  tanhF, 512);
  hipLaunchKernelGGL(k_proj, dim3(128, 2), dim3(256), 0, stream, audioF, packA, audioB, tanhA, 256);

  hipLaunchKernelGGL(k_attdot, dim3(256), dim3(256), 0, stream,
                     tanhT, tanhF, tanhA, attW, utW, ufW, uaW, s6);
  hipLaunchKernelGGL(k_zerofeed, dim3(64), dim3(256), 0, stream, encfeed);
  hipLaunchKernelGGL(k_smax, dim3(96), dim3(256), 0, stream, s6, attn_tb, encfeed);

  // fused pipelined 4-LSTM: 3 encoder pairs + 1 decoder pair = 8 blocks
  hipLaunchKernelGGL(k_lstm, dim3(8), dim3(512), 0, stream,
                     packL, encfeed, target, attn_tb, encOutW, encOutB,
                     decH0, decC0, dec_h, exch, partials);
  hipLaunchKernelGGL(k_decout, dim3(256), dim3(256), 0, stream,
                     dec_h, out1W, out1B, out2W, out2B, out);
}